// Round 18
// baseline (496.887 us; speedup 1.0000x reference)
//
#include <hip/hip_runtime.h>
#include <hip/hip_bf16.h>

// Problem constants
constexpr int Bb = 256;   // batch
constexpr int Nn = 512;   // nodes
constexpr int Dd = 512;   // model dim
constexpr int Hh = 8;     // heads
constexpr int Tt = 128;   // steps
#define NEGF (-1.0e9f)

typedef __attribute__((ext_vector_type(4))) float f32x4;
typedef __attribute__((ext_vector_type(8))) short bf16x8;     // MFMA a/b frag (8 bf16)
typedef __attribute__((ext_vector_type(8))) unsigned short u16x8;

#define AS1 __attribute__((address_space(1)))
#define AS3 __attribute__((address_space(3)))

__device__ __forceinline__ unsigned short f2bf(float f) {
  union { float f; unsigned u; } v; v.f = f;
  unsigned r = v.u + 0x7fffu + ((v.u >> 16) & 1u);   // RNE
  return (unsigned short)(r >> 16);
}

__device__ __forceinline__ unsigned cvtpk(float lo, float hi) {
  unsigned r;
  asm("v_cvt_pk_bf16_f32 %0, %1, %2" : "=v"(r) : "v"(lo), "v"(hi));
  return r;
}

__device__ __forceinline__ void cast8(const float* __restrict__ src,
                                      unsigned short* __restrict__ dst, int i) {
  const float4* s = (const float4*)src + (size_t)i * 2;
  float4 a = s[0], b = s[1];
  u16x8 o;
  o[0] = f2bf(a.x); o[1] = f2bf(a.y); o[2] = f2bf(a.z); o[3] = f2bf(a.w);
  o[4] = f2bf(b.x); o[5] = f2bf(b.y); o[6] = f2bf(b.z); o[7] = f2bf(b.w);
  ((u16x8*)dst)[i] = o;
}

// ======== prep_k: fused prologue (casts + mask bitmask + weight transpose-casts) ========
__global__ void prep_k(const float* __restrict__ emb, const int* __restrict__ mask,
                       const float* __restrict__ Wkt, const float* __restrict__ Wout,
                       const float* __restrict__ mge,
                       const float* __restrict__ Wk, const float* __restrict__ Wv,
                       const float* __restrict__ Wqs, const float* __restrict__ Wqc,
                       unsigned short* __restrict__ embB, unsigned* __restrict__ bits,
                       unsigned short* __restrict__ WktB, unsigned short* __restrict__ WoutB,
                       unsigned short* __restrict__ mgeB,
                       unsigned short* __restrict__ WkT, unsigned short* __restrict__ WvT,
                       unsigned short* __restrict__ WqsT, unsigned short* __restrict__ WqcT) {
  __shared__ float t[32][33];
  int bid = blockIdx.x, tid = threadIdx.x;
  if (bid < 32768) {
    cast8(emb, embB, bid * 256 + tid);
  } else if (bid < 98304) {
    size_t gid = (size_t)(bid - 32768) * 256 + tid;
    int mv = mask[gid];
    unsigned long long bal = __ballot(mv == 1);
    if ((tid & 63) == 0) {
      unsigned tt = (unsigned)(gid >> 17);
      unsigned b = (unsigned)((gid >> 9) & 255);
      unsigned n = (unsigned)(gid & 511);
      unsigned* dst = bits + (((size_t)b * 128 + tt) * 16 + (n >> 5));
      dst[0] = (unsigned)bal;
      dst[1] = (unsigned)(bal >> 32);
    }
  } else if (bid < 98432) {
    cast8(Wkt, WktB, (bid - 98304) * 256 + tid);
  } else if (bid < 98560) {
    cast8(Wout, WoutB, (bid - 98432) * 256 + tid);
  } else if (bid < 98624) {
    cast8(mge, mgeB, (bid - 98560) * 256 + tid);
  } else {
    int vb = bid - 98624;
    int mid = vb >> 8;
    int tile = vb & 255;
    const float* S = (mid == 0) ? Wk : (mid == 1) ? Wv : (mid == 2) ? Wqs : Wqc;
    unsigned short* Dst = (mid == 0) ? WkT : (mid == 1) ? WvT : (mid == 2) ? WqsT : WqcT;
    int r0 = (tile >> 4) * 32, c0 = (tile & 15) * 32;
    int tx = tid & 31, ty = tid >> 5;
#pragma unroll
    for (int yy = 0; yy < 4; ++yy) {
      int r = ty + yy * 8;
      t[r][tx] = S[(size_t)(r0 + r) * 512 + c0 + tx];
    }
    __syncthreads();
#pragma unroll
    for (int yy = 0; yy < 4; ++yy) {
      int c = ty + yy * 8;
      Dst[(size_t)(c0 + c) * 512 + r0 + tx] = f2bf(t[tx][c]);   // Dst[n][k] = W[k][n]
    }
  }
}

// ---------------- shared staging: 128x64 bf16 tile via global_load_lds (16B) ----------------
__device__ __forceinline__ void stage_tile(const unsigned short* __restrict__ G, int row0, int k0,
                                           unsigned short* lds_base, int wave, int lane) {
#pragma unroll
  for (int c = 0; c < 4; ++c) {
    int chunk = wave * 4 + c;                       // 16 chunks of 1KB (8 rows each)
    const unsigned short* g = G + (size_t)(row0 + chunk * 8 + (lane >> 3)) * 512 + k0 + (lane & 7) * 8;
    __builtin_amdgcn_global_load_lds((AS1 void*)g, (AS3 void*)(lds_base + chunk * 512), 16, 0, 0);
  }
}

// ======== wfqc_k: merged tiny GEMMs — blocks 0-15: WFT=WktB@WoutB^T (bf16);
//          blocks 16-23: Qc=mgeB@WqcT^T (f32) ========
__global__ __launch_bounds__(256, 2)
void wfqc_k(const unsigned short* __restrict__ A0, const unsigned short* __restrict__ BT0,
            unsigned short* __restrict__ C0,
            const unsigned short* __restrict__ A1, const unsigned short* __restrict__ BT1,
            float* __restrict__ C1) {
  __shared__ __align__(16) char lds[32768];
  unsigned short* ldsA = (unsigned short*)lds;
  unsigned short* ldsB = ldsA + 8192;
  int bid = blockIdx.x;
  bool qc = (bid >= 16);
  int lb = qc ? bid - 16 : bid;
  const unsigned short* A = qc ? A1 : A0;
  const unsigned short* BT = qc ? BT1 : BT0;
  int mt = lb >> 2, nt = lb & 3;
  int m0 = mt * 128, n0 = nt * 128;
  int tid = threadIdx.x, lane = tid & 63, w = tid >> 6;
  int wm = w >> 1, wn = w & 1;
  int l15 = lane & 15, l4 = lane >> 4;

  f32x4 acc[4][4] = {};
  for (int k0 = 0; k0 < 512; k0 += 64) {
    stage_tile(A, m0, k0, ldsA, w, lane);
    stage_tile(BT, n0, k0, ldsB, w, lane);
    __syncthreads();
#pragma unroll
    for (int ks = 0; ks < 2; ++ks) {
      bf16x8 fa[4], fb[4];
#pragma unroll
      for (int ii = 0; ii < 4; ++ii)
        fa[ii] = *(const bf16x8*)(ldsA + (wm * 64 + ii * 16 + l15) * 64 + ks * 32 + l4 * 8);
#pragma unroll
      for (int jj = 0; jj < 4; ++jj)
        fb[jj] = *(const bf16x8*)(ldsB + (wn * 64 + jj * 16 + l15) * 64 + ks * 32 + l4 * 8);
#pragma unroll
      for (int ii = 0; ii < 4; ++ii)
#pragma unroll
        for (int jj = 0; jj < 4; ++jj)
          acc[ii][jj] = __builtin_amdgcn_mfma_f32_16x16x32_bf16(fa[ii], fb[jj], acc[ii][jj], 0, 0, 0);
    }
    __syncthreads();
  }
#pragma unroll
  for (int ii = 0; ii < 4; ++ii)
#pragma unroll
    for (int jj = 0; jj < 4; ++jj)
#pragma unroll
      for (int r = 0; r < 4; ++r) {
        int row = m0 + wm * 64 + ii * 16 + l4 * 4 + r;
        int col = n0 + wn * 64 + jj * 16 + l15;
        if (qc) C1[(size_t)row * 512 + col] = acc[ii][jj][r];
        else C0[(size_t)row * 512 + col] = f2bf(acc[ii][jj][r]);
      }
}

// ---------------- shared 8-phase macros (proven in gemm8f/gemm10/gemm11) ----------------
#define LDA_Q(QM)                                                   \
  _Pragma("unroll")                                                 \
  for (int ii = 0; ii < 4; ++ii) {                                  \
    int rr_ = (QM) * 64 + ii * 16 + l15;                            \
    const char* ap_ = ldsAh + rr_ * 128;                            \
    int sw_ = (rr_ & 7) << 4;                                       \
    fa[ii][0] = *(const bf16x8*)(ap_ + ((l4 * 16) ^ sw_));          \
    fa[ii][1] = *(const bf16x8*)(ap_ + ((64 + l4 * 16) ^ sw_));     \
  }

#define LDB_Q(QN)                                                   \
  _Pragma("unroll")                                                 \
  for (int jj = 0; jj < 2; ++jj) {                                  \
    int rr_ = (wn & 1) * 64 + (QN) * 32 + jj * 16 + l15;            \
    const char* bp_ = ldsBh + rr_ * 128;                            \
    int sw_ = (rr_ & 7) << 4;                                       \
    fb[jj][0] = *(const bf16x8*)(bp_ + ((l4 * 16) ^ sw_));          \
    fb[jj][1] = *(const bf16x8*)(bp_ + ((64 + l4 * 16) ^ sw_));     \
  }

#define MM16(QM, QN)                                                              \
  do {                                                                            \
    __builtin_amdgcn_s_setprio(1);                                                \
    _Pragma("unroll")                                                             \
    for (int ii = 0; ii < 4; ++ii)                                                \
      _Pragma("unroll")                                                           \
      for (int jj = 0; jj < 2; ++jj) {                                            \
        acc[(QM) * 4 + ii][(QN) * 2 + jj] = __builtin_amdgcn_mfma_f32_16x16x32_bf16( \
            fa[ii][0], fb[jj][0], acc[(QM) * 4 + ii][(QN) * 2 + jj], 0, 0, 0);    \
        acc[(QM) * 4 + ii][(QN) * 2 + jj] = __builtin_amdgcn_mfma_f32_16x16x32_bf16( \
            fa[ii][1], fb[jj][1], acc[(QM) * 4 + ii][(QN) * 2 + jj], 0, 0, 0);    \
      }                                                                           \
    __builtin_amdgcn_s_setprio(0);                                                \
  } while (0)

// gemm10 staging (persistent double GEMM part)
#define STAGE10A(SLOT, H, ROWB, KT)                                               \
  do {                                                                             \
    int rb_ = (ROWB) + (H) * 128;                                                  \
    char* Lb_ = lds + (SLOT) * 32768 + (H) * 16384;                                \
    _Pragma("unroll")                                                              \
    for (int sh_ = 0; sh_ < 2; ++sh_) {                                            \
      int off_ = sh_ * 8192 + tid * 16;                                            \
      int r_ = off_ >> 7;                                                          \
      int c_ = (off_ & 127) ^ ((r_ & 7) << 4);                                     \
      const char* g_ = (const char*)(A + (size_t)(rb_ + r_) * 512 + (KT) * 64) + c_; \
      __builtin_amdgcn_global_load_lds((AS1 void*)g_, (AS3 void*)(Lb_ + off_), 16, 0, 0); \
    }                                                                              \
  } while (0)

#define STAGE10B(SLOT, H, KT)                                                      \
  do {                                                                             \
    int rb_ = n0 + (H) * 128;                                                      \
    char* Lb_ = lds + 98304 + (SLOT) * 32768 + (H) * 16384;                        \
    _Pragma("unroll")                                                              \
    for (int sh_ = 0; sh_ < 2; ++sh_) {                                            \
      int off_ = sh_ * 8192 + tid * 16;                                            \
      int r_ = off_ >> 7;                                                          \
      int c_ = (off_ & 127) ^ ((r_ & 7) << 4);                                     \
      const char* g_ = (const char*)(BT + (size_t)(rb_ + r_) * 512 + (KT) * 64) + c_; \
      __builtin_amdgcn_global_load_lds((AS1 void*)g_, (AS3 void*)(Lb_ + off_), 16, 0, 0); \
    }                                                                              \
  } while (0)

// gemm11 staging (single-tile q/mh2 part; A via per-thread bases, supports gather)
#define STAGE11A(SLOT, H, KT)                                                      \
  do {                                                                             \
    char* Lb_ = lds + (SLOT) * 65536 + (H) * 16384;                                \
    __builtin_amdgcn_global_load_lds((AS1 void*)(abase[(H) * 2 + 0] + (KT) * 128), \
        (AS3 void*)(Lb_ + tid * 16), 16, 0, 0);                                    \
    __builtin_amdgcn_global_load_lds((AS1 void*)(abase[(H) * 2 + 1] + (KT) * 128), \
        (AS3 void*)(Lb_ + 8192 + tid * 16), 16, 0, 0);                             \
  } while (0)

#define STAGE11B(SLOT, H, KT)                                                      \
  do {                                                                             \
    int rb_ = n0 + (H) * 128;                                                      \
    char* Lb_ = lds + (SLOT) * 65536 + 32768 + (H) * 16384;                        \
    _Pragma("unroll")                                                              \
    for (int sh_ = 0; sh_ < 2; ++sh_) {                                            \
      int off_ = sh_ * 8192 + tid * 16;                                            \
      int r_ = off_ >> 7;                                                          \
      int c_ = (off_ & 127) ^ ((r_ & 7) << 4);                                     \
      const char* g_ = (const char*)(BT + (size_t)(rb_ + r_) * 512 + (KT) * 64) + c_; \
      __builtin_amdgcn_global_load_lds((AS1 void*)g_, (AS3 void*)(Lb_ + off_), 16, 0, 0); \
    }                                                                              \
  } while (0)

// ======== gemmq_k: FUSED dispatch. blocks [0,256): gemm11<3> (Qb, gathered A).
//          blocks [256,768): gemm10 persistent double GEMM (Kb + Vt). ========
__global__ __launch_bounds__(512, 1)
void gemmq_k(const unsigned short* __restrict__ embB,
             const unsigned short* __restrict__ WqsT,
             unsigned short* __restrict__ Qb,
             const float* __restrict__ Qc, const float* __restrict__ WqsL,
             const float* __restrict__ capp, const int* __restrict__ prev,
             const unsigned short* __restrict__ B0, const unsigned short* __restrict__ B1,
             unsigned short* __restrict__ C0, unsigned short* __restrict__ C2) {
  __shared__ __align__(16) char lds[163840];
  int tid = threadIdx.x, lane = tid & 63, w = tid >> 6;
  int l15 = lane & 15, l4 = lane >> 4;

  if (blockIdx.x < 256) {
    // ---------------- gemm11<3>: Qb projection with gathered A rows ----------------
    const unsigned short* A = embB;
    const unsigned short* BT = WqsT;
    int xcd = blockIdx.x & 7, loc = blockIdx.x >> 3;   // loc < 32
    int mt = xcd * 16 + (loc >> 1), nh = loc & 1;
    int m0 = mt * 256, n0 = nh * 256;
    int wm = w >> 2, wn = w & 3;

    const char* abase[4];
#pragma unroll
    for (int hs = 0; hs < 4; ++hs) {
      int H = hs >> 1, sh = hs & 1;
      int off = sh * 8192 + tid * 16;
      int r = off >> 7;
      int c = (off & 127) ^ ((r & 7) << 4);
      int row = m0 + H * 128 + r;
      int t = row >> 8, bb = row & 255;
      int pa = prev[t * Bb + bb];
      abase[hs] = (const char*)(A + (size_t)(bb * 512 + pa) * 512) + c;
    }

    f32x4 acc[8][4] = {};
    bf16x8 fa[4][2], fb[2][2];

    STAGE11A(0, 0, 0); STAGE11A(0, 1, 0);
    STAGE11B(0, 0, 0); STAGE11B(0, 1, 0);

    for (int kt = 0; kt < 8; ++kt) {
      int s = kt & 1, sn = s ^ 1;
      char* ldsAh = lds + s * 65536 + wm * 16384;
      char* ldsBh = lds + s * 65536 + 32768 + (wn >> 1) * 16384;
      if (kt < 7) {
        STAGE11A(sn, 0, kt + 1);
        asm volatile("s_waitcnt vmcnt(2)" ::: "memory");
      } else {
        asm volatile("s_waitcnt vmcnt(0)" ::: "memory");
      }
      __builtin_amdgcn_s_barrier();
      LDA_Q(0); LDB_Q(0);
      MM16(0, 0);
      __builtin_amdgcn_s_barrier();
      LDB_Q(1);
      if (kt < 7) STAGE11A(sn, 1, kt + 1);
      __builtin_amdgcn_s_barrier();
      MM16(0, 1);
      __builtin_amdgcn_s_barrier();
      LDA_Q(1);
      if (kt < 7) STAGE11B(sn, 0, kt + 1);
      __builtin_amdgcn_s_barrier();
      MM16(1, 1);
      __builtin_amdgcn_s_barrier();
      LDB_Q(0);
      if (kt < 7) STAGE11B(sn, 1, kt + 1);
      __builtin_amdgcn_s_barrier();
      MM16(1, 0);
      __builtin_amdgcn_s_barrier();
    }

#pragma unroll
    for (int mi = 0; mi < 8; ++mi)
#pragma unroll
      for (int nj = 0; nj < 4; ++nj)
#pragma unroll
        for (int r = 0; r < 4; ++r) {
          int row = m0 + wm * 128 + mi * 16 + l4 * 4 + r;
          int col = n0 + wn * 64 + nj * 16 + l15;
          int t = row >> 8, bbx = row & 255;
          float val = acc[mi][nj][r] + Qc[(size_t)bbx * 512 + col] + (1.0f - capp[row]) * WqsL[col];
          Qb[(size_t)(bbx * 128 + t) * 512 + col] = f2bf(val * 0.125f);
        }
  } else {
    // ---------------- gemm10: persistent 4-tile fused double GEMM (K / V^T) ----------------
    const unsigned short* A = embB;
    int bid = blockIdx.x - 256;
    int xcd = bid & 7, loc = bid >> 3;   // loc < 64
    int ml4 = loc >> 2, cmb = loc & 3;
    int grp = cmb >> 1, nh = cmb & 1;
    const unsigned short* BT = grp ? B1 : B0;
    int mtb = xcd * 64 + ml4 * 4;
    int n0 = nh * 256;
    int wm = w >> 2, wn = w & 3;

    f32x4 acc[8][4] = {};
    bf16x8 fa[4][2], fb[2][2];

    {
      int m00 = mtb * 256;
      STAGE10A(0, 0, m00, 0); STAGE10A(0, 1, m00, 0);
      STAGE10A(1, 0, m00, 1); STAGE10A(1, 1, m00, 1);
      STAGE10B(0, 0, 0);      STAGE10B(0, 1, 0);
    }

    for (int g = 0; g < 32; ++g) {
      int As = g % 3, Astg = (g + 2) % 3;
      int Bs = g & 1, Bstg = Bs ^ 1;
      char* ldsAh = lds + As * 32768 + wm * 16384;
      char* ldsBh = lds + 98304 + Bs * 32768 + (wn >> 1) * 16384;
      int g2 = g + 2;
      int m0A = (mtb + (g2 >> 3)) * 256, ktA = g2 & 7;
      int ktB = (g + 1) & 7;
      if (g < 30) {
        STAGE10A(Astg, 0, m0A, ktA);
        asm volatile("s_waitcnt vmcnt(2)" ::: "memory");
      } else {
        asm volatile("s_waitcnt vmcnt(0)" ::: "memory");
      }
      __builtin_amdgcn_s_barrier();
      LDA_Q(0); LDB_Q(0);
      MM16(0, 0);
      __builtin_amdgcn_s_barrier();
      LDB_Q(1);
      if (g < 30) STAGE10A(Astg, 1, m0A, ktA);
      __builtin_amdgcn_s_barrier();
      MM16(0, 1);
      __builtin_amdgcn_s_barrier();
      LDA_Q(1);
      if (g < 31) STAGE10B(Bstg, 0, ktB);
      __builtin_amdgcn_s_barrier();
      MM16(1, 1);
      __builtin_amdgcn_s_barrier();
      LDB_Q(0);
      if (g < 31) STAGE10B(Bstg, 1, ktB);
      __builtin_amdgcn_s_barrier();
      MM16(1, 0);
      __builtin_amdgcn_s_barrier();

      if ((g & 7) == 7) {
        int m0cur = (mtb + (g >> 3)) * 256;
        if (grp == 0) {
#pragma unroll
          for (int mi = 0; mi < 8; ++mi)
#pragma unroll
            for (int nj = 0; nj < 4; ++nj)
#pragma unroll
              for (int r = 0; r < 4; ++r) {
                int row = m0cur + wm * 128 + mi * 16 + l4 * 4 + r;
                int col = n0 + wn * 64 + nj * 16 + l15;
                C0[(size_t)row * 512 + col] = f2bf(acc[mi][nj][r]);
              }
        } else {
          int bb = m0cur >> 9, nn0 = m0cur & 511;
          char* wb = lds + As * 32768 + w * 4096;
          int rdrow = lane >> 3, nseg = lane & 7;
#pragma unroll
          for (int p = 0; p < 8; ++p) {
            int nj = p >> 1;
            if ((l15 >> 3) == (p & 1)) {
              int rowL = l15 & 7;
#pragma unroll
              for (int mi = 0; mi < 8; ++mi) {
                ushort4 w4;
                w4.x = f2bf(acc[mi][nj][0]);
                w4.y = f2bf(acc[mi][nj][1]);
                w4.z = f2bf(acc[mi][nj][2]);
                w4.w = f2bf(acc[mi][nj][3]);
                *(ushort4*)(wb + rowL * 272 + (mi * 16 + l4 * 4) * 2) = w4;
              }
            }
            asm volatile("s_waitcnt lgkmcnt(0)" ::: "memory");
            u16x8 v0 = *(const u16x8*)(wb + rdrow * 272 + nseg * 16);
            u16x8 v1 = *(const u16x8*)(wb + rdrow * 272 + 128 + nseg * 16);
            int dglob = n0 + wn * 64 + p * 8 + rdrow;
            unsigned short* dp = C2 + (size_t)(bb * 512 + dglob) * 512 + nn0 + wm * 128;
            *(u16x8*)(dp + nseg * 8) = v0;
            *(u16x8*)(dp + 64 + nseg * 8) = v1;
            asm volatile("s_waitcnt lgkmcnt(0)" ::: "memory");
          }
        }
#pragma unroll
        for (int mi = 0; mi < 8; ++mi)
#pragma unroll
          for (int nj = 0; nj < 4; ++nj)
            acc[mi][nj] = (f32x4){0.f, 0.f, 0.f, 0.f};
        __syncthreads();
      }
    }
  }
}

// ======== gemm11<1>: 256x256 8-phase single-tile GEMM (mh2 = mhaB @ WFT^T) ========
__global__ __launch_bounds__(512, 1)
void gemm11_k(const unsigned short* __restrict__ A, const unsigned short* __restrict__ BT,
              unsigned short* __restrict__ C) {
  __shared__ __align__(16) char lds[131072];
  int xcd = blockIdx.x & 7, loc = blockIdx.x >> 3;   // loc < 32
  int mt = xcd * 16 + (loc >> 1), nh = loc & 1;
  int m0 = mt * 256, n0 = nh * 256;
  int tid = threadIdx.x, lane = tid & 63, w = tid >> 6;
  int wm = w >> 2, wn = w & 3;
  int l15 = lane & 15, l4 = lane >> 4;

  const char* abase[4];
#pragma unroll
  for (int hs = 0; hs < 4; ++hs) {
    int H = hs >> 1, sh = hs & 1;
    int off = sh * 8192 + tid * 16;
    int r = off >> 7;
    int c = (off & 127) ^ ((r & 7) << 4);
    int row = m0 + H * 128 + r;
    abase[hs] = (const char*)(A + (size_t)row * 512) + c;
  }

  f32x4 acc[8][4] = {};
  bf16x8 fa[4][2], fb[2][2];

  STAGE11A(0, 0, 0); STAGE11A(0, 1, 0);
  STAGE11B(0, 0, 0); STAGE11B(0, 1, 0);

  for (int kt = 0; kt < 8; ++kt) {
    int s = kt & 1, sn = s ^ 1;
    char* ldsAh = lds + s * 65536 + wm * 16384;
    char* ldsBh = lds + s * 65536 + 32768 + (wn >> 1) * 16384;
    if (kt < 7) {
      STAGE11A(sn, 0, kt + 1);
      asm volatile("s_waitcnt vmcnt(2)" ::: "memory");
    } else {
      asm volatile("s_waitcnt vmcnt(0)" ::: "memory");
    }
    __builtin_amdgcn_s_barrier();
    LDA_Q(0); LDB_Q(0);
    MM16(0, 0);
    __builtin_amdgcn_s_barrier();
    LDB_Q(1);
    if (kt < 7) STAGE11A(sn, 1, kt + 1);
    __builtin_amdgcn_s_barrier();
    MM16(0, 1);
    __builtin_amdgcn_s_barrier();
    LDA_Q(1);
    if (kt < 7) STAGE11B(sn, 0, kt + 1);
    __builtin_amdgcn_s_barrier();
    MM16(1, 1);
    __builtin_amdgcn_s_barrier();
    LDB_Q(0);
    if (kt < 7) STAGE11B(sn, 1, kt + 1);
    __builtin_amdgcn_s_barrier();
    MM16(1, 0);
    __builtin_amdgcn_s_barrier();
  }

#pragma unroll
  for (int mi = 0; mi < 8; ++mi)
#pragma unroll
    for (int nj = 0; nj < 4; ++nj)
#pragma unroll
      for (int r = 0; r < 4; ++r) {
        int row = m0 + wm * 128 + mi * 16 + l4 * 4 + r;
        int col = n0 + wn * 64 + nj * 16 + l15;
        C[(size_t)row * 512 + col] = f2bf(acc[mi][nj][r]);
      }
}

// ================= attn5: LDS-staged chunked flash pipeline =================
#define STAGEK5(CH, SLOT)                                                          \
  do {                                                                             \
    _Pragma("unroll")                                                              \
    for (int sh_ = 0; sh_ < 2; ++sh_) {                                            \
      int off_ = sh_ * 8192 + tid * 16;                                            \
      int r_ = off_ >> 7;                                                          \
      int c_ = (off_ & 127) ^ ((r_ & 7) << 4);                                     \
      const char* g_ = (const char*)(Kb + (size_t)(b * 512 + (CH) * 128 + r_) * 512 + h * 64) + c_; \
      __builtin_amdgcn_global_load_lds((AS1 void*)g_, (AS3 void*)(lds + (SLOT) * 16384 + off_), 16, 0, 0); \
    }                                                                              \
  } while (0)

#define STAGEV5(CH, SLOT)                                                          \
  do {                                                                             \
    _Pragma("unroll")                                                              \
    for (int sh_ = 0; sh_ < 2; ++sh_) {                                            \
      int off_ = sh_ * 8192 + tid * 16;                                            \
      int r_ = off_ >> 8;                                                          \
      int c_ = (off_ & 255) ^ ((r_ & 7) << 4);                                     \
      const char* g_ = (const char*)(Vt + (size_t)(b * 512 + h * 64 + r_) * 512 + (CH) * 128) + c_; \
      __builtin_amdgcn_global_load_lds((AS1 void*)g_, (AS3 void*)(lds + 32768 + (SLOT) * 16384 + off_), 16, 0, 0); \
    }                                                                              \
  } while (0)

#define CHUNK5(CH)                                                                 \
  do {                                                                             \
    const char* Ks_ = lds + ((CH) & 1) * 16384;                                    \
    const char* Vs_ = lds + 32768 + ((CH) & 1) * 16384;                            \
    f32x4 sck[8];                                                                  \
    _Pragma("unroll")                                                              \
    for (int jj = 0; jj < 8; ++jj) sck[jj] = (f32x4){0.f, 0.f, 0.f, 0.f};          \
    _Pragma("unroll")                                                              \
    for (int jj = 0; jj < 8; ++jj) {                                               \
      int rr_ = jj * 16 + l15;                                                     \
      int sw_ = (rr_ & 7) << 4;                                                    \
      bf16x8 k0_ = *(const bf16x8*)(Ks_ + rr_ * 128 + ((l4 * 16) ^ sw_));          \
      bf16x8 k1_ = *(const bf16x8*)(Ks_ + rr_ * 128 + ((64 + l4 * 16) ^ sw_));     \
      sck[jj] = __builtin_amdgcn_mfma_f32_16x16x32_bf16(k0_, fq[0], sck[jj], 0, 0, 0); \
      sck[jj] = __builtin_amdgcn_mfma_f32_16x16x32_bf16(k1_, fq[1], sck[jj], 0, 0, 0); \
    }                                                                              \
    unsigned mwarr_[4] = {mqs[CH].x, mqs[CH].y, mqs[CH].z, mqs[CH].w};             \
    float cmx_ = -3.0e38f;                                                         \
    _Pragma("unroll")                                                              \
    for (int jj = 0; jj < 8; ++jj) {                                               \
      unsigned nib_ = mwarr_[jj >> 1] >> (((jj & 1) << 4) + (l4 << 2));            \
      _Pragma("unroll")                                                            \
      for (int r = 0; r < 4; ++r)                                                  \
        sck[jj][r] = ((nib_ >> r) & 1) ? NEGF : sck[jj][r];                        \
      float m01_ = fmaxf(sck[jj][0], sck[jj][1]);                                  \
      float m23_ = fmaxf(sck[jj][2], sck[jj][3]);                                  \
      cmx_ = fmaxf(cmx_, fmaxf(m01_, m23_));                                       \
    }                                                                              \
    cmx_ = fmaxf(cmx_, __shfl_xor(cmx_, 16));                                      \
    cmx_ = fmaxf(cmx_, __shfl_xor(cmx_, 32));                                      \
    float mn_ = fmaxf(mx, cmx_);                                                   \
    float al_ = __expf(mx - mn_);                                                  \
    sum *= al_;                                                                    \
    _Pragma("unroll")                                                              \
    for (int dj = 0; dj < 4; ++dj)                                                 \
      _Pragma("unroll")                                                            \
      for (int r = 0; r < 4; ++r) o[dj][r] *= al_;                                 \
    mx = mn_;                                                                      \
    _Pragma("unroll")                                                              \
    for (int jj = 0; jj < 8; ++jj) {                                               \
      _Pragma("unroll")                                                            \
      for (int r = 0; r < 4; ++r) sck[jj][r] = __expf(sck[jj][r] - mx);            \
      sum += (sck[jj][0] + sck[jj][1]) + (sck[jj][2] + sck[jj][3]);                \
    }                                                                              \
    _Pragma("unroll")                                                              \
    for (int g = 0; g < 4; ++g) {                                                  \
      unsigned a0_ = cvtpk(sck[2 * g][0], sck[2 * g][1]);                          \
      unsigned a1_ = cvtpk(sck[2 * g][2], sck[2 * g][3]);                          \
      unsigned b0_ = cvtpk(sck[2 * g + 1][0], sck[2 * g + 1][1]);                  \
      unsigned b1_ = cvtpk(sck[2 * g + 1][2], sck[2 * g + 1][3]);                  \
      unsigned wA0_ = __shfl(a0_, src0, 64), wB0_ = __shfl(b0_, src0, 64);         \
      unsigned wA1_ = __shfl(a1_, src0, 64), wB1_ = __shfl(b1_, src0, 64);         \
      unsigned wA2_ = __shfl(a0_, src2, 64), wB2_ = __shfl(b0_, src2, 64);         \
      unsigned wA3_ = __shfl(a1_, src2, 64), wB3_ = __shfl(b1_, src2, 64);         \
      union { unsigned u[4]; bf16x8 v; } pu_;                                      \
      pu_.u[0] = loh ? wA0_ : wB0_;                                                \
      pu_.u[1] = loh ? wA1_ : wB1_;                                                \
      pu_.u[2] = loh ? wA2_ : wB2_;                                                \
      pu_.u[3] = loh ? wA3_ : wB3_;                                                \
      _Pragma("unroll")                                                            \
      for (int dj = 0; dj < 4; ++dj) {                                             \
        int rr_ = dj * 16 + l15;                                                   \
        int sw_ = (rr_ & 7) << 4;                                                  \
        bf16x8 fv_ = *(const bf16x8*)(Vs_ + rr_ * 256 + ((g * 64 + l4 * 16) ^ sw_)); \
        o[dj] = __builtin_amdgcn_mfma_f32_16x16x32_bf16(fv_, pu_.v, o[dj], 0, 0, 0); \
      }                                                                            \
    }                                                                              \
  } while (0)

__global__ __launch_bounds__(512, 4)
void attn5_k(const unsigned short* __restrict__ Qb, const unsigned short* __restrict__ Kb,
             const unsigned short* __restrict__ Vt, const unsigned* __restrict__ mbits,
             unsigned short* __restrict__ mhaB) {
  __shared__ __align__(16) char lds[65536];
  int bid = blockIdx.x;
  int h = bid & 7, b = bid >> 3;
  int tid = threadIdx.x, lane = tid & 63, w = tid >> 6;
  int l15 = lane & 15, l4 = lane >> 4;
  int t = w * 16 + l15;

  bf16x8 fq[2];
#pragma unroll
  for (int ks = 0; ks < 2; ++ks)
    fq[ks] = *(const bf16x8*)(Qb + (size_t)(b * 128 + t) * 512 + h * 64 + ks * 32 + l4 * 8);
  uint4 mqs[4];
  {
    const uint4* mp = (const uint4*)(mbits + (((size_t)b * 128 + t) << 4));
    mqs[0] = mp[0]; mqs[1] = mp[1]; mqs[2] = mp[2]; mqs[3] = mp[3];
  }

  float mx = -3.0e38f, sum = 0.f;
  f32x4 o[4] = {};
  int src0 = l15 + ((l4 & 1) ? 32 : 0);
  int src2 = l15 + ((l4 & 1) ? 48 : 16);
  bool loh = (l4 < 2);

  STAGEK5(0, 0); STAGEV5(0, 0);
  STAGEK5(1, 1); STAGEV5(1, 1);
  asm volatile("s_waitcnt vmcnt(4)" ::: "memory");
  __builtin_amdgcn_s_barrier();
  CHUNK5(0);
  __builtin_amdgcn_s_barrier();
  STAGEK5(2, 0); STAGEV5(2, 0);
  asm volatile("s_waitcnt vmcnt(4)" ::: "memory");
  __builtin_amdgcn_s_barrier();
  CHUNK5(1);
  __builtin_amdgcn_s_barrier();
  STAGEK5(3, 1); STAGEV5(3, 1);
  asm volatile("s_waitcnt vmcnt(4)" ::: "memory");
  __builtin_amdgcn_s_barrier();
  CHUNK5(2);
  __builtin_amdgcn_s_barrier();
  asm volatile("s_waitcnt vmcnt(0)" ::: "memory");
  __builtin_amdgcn_s_barrier();
  CHUNK5(3);

  sum += __shfl_xor(sum, 16);
  sum += __shfl_xor(sum, 32);
  float inv = 1.0f / sum;
#pragma unroll
  for (int dj = 0; dj < 4; ++dj) {
    ushort4 w4;
    w4.x = f2bf(o[dj][0] * inv);
    w4.y = f2bf(o[dj][1] * inv);
    w4.z = f2bf(o[dj][2] * inv);
    w4.w = f2bf(o[dj][3] * inv);
    *(ushort4*)(mhaB + (size_t)(b * 128 + t) * 512 + h * 64 + dj * 16 + l4 * 4) = w4;
  }
}

// ========= comp6: t-split pointer logits with FUSED normalization =========
// block = (b, t-half): 256 thr = 4 waves x 16 t.  Full n=512 per block -> complete
// row sums in-block; unnormalized p written during chunks, then L2-hot in-place rescale.
#define STAGEC6(CH, SLOT)                                                          \
  do {                                                                             \
    _Pragma("unroll")                                                              \
    for (int ps_ = 0; ps_ < 4; ++ps_) {                                            \
      int off_ = ps_ * 4096 + tid * 16;                                            \
      int r_ = off_ >> 10;                                                         \
      int c_ = (off_ & 1023) ^ ((r_ & 7) << 4);                                    \
      const char* g_ = (const char*)(embB + (size_t)(b * 512 + (CH) * 16 + r_) * 512) + c_; \
      __builtin_amdgcn_global_load_lds((AS1 void*)g_, (AS3 void*)(lds + (SLOT) * 16384 + off_), 16, 0, 0); \
    }                                                                              \
  } while (0)

#define CCHUNK6(CH)                                                               \
  do {                                                                             \
    const char* Es_ = lds + ((CH) & 1) * 16384;                                    \
    f32x4 sck = (f32x4){0.f, 0.f, 0.f, 0.f};                                       \
    int rr_ = l15;                                                                 \
    const char* ep_ = Es_ + rr_ * 1024;                                            \
    int sw_ = (rr_ & 7) << 4;                                                      \
    _Pragma("unroll")                                                              \
    for (int ks_ = 0; ks_ < 16; ++ks_) {                                           \
      bf16x8 fa_ = *(const bf16x8*)(ep_ + ((ks_ * 64 + l4 * 16) ^ sw_));           \
      sck = __builtin_amdgcn_mfma_f32_16x16x32_bf16(fa_, fb[ks_], sck, 0, 0, 0);   \
    }                                                                              \
    unsigned nib_ = mw[(CH) >> 1] >> ((((CH) & 1) << 4) + (l4 << 2));              \
    float4 o4_;                                                                    \
    float* po_ = (float*)&o4_;                                                     \
    _Pragma("unroll")                                                              \
    for (int r = 0; r < 4; ++r) {                                                  \
      float y_ = sck[r] * 0.044194173824159216f;                                   \
      y_ = fminf(fmaxf(y_, -15.f), 15.f);                                          \
      float e2_ = __expf(2.f * y_);                                                \
      float th_ = (e2_ - 1.f) / (e2_ + 1.f);                                       \
      float p_ = __expf(th_ * 10.f - 10.f);                                        \
      p_ = ((nib_ >> r) & 1) ? 0.f : p_;                                           \
      po_[r] = p_;                                                                 \
      sum += p_;                                                                   \
    }                                                                              \
    *(float4*)(out + (size_t)(b * 128 + t) * 512 + (CH) * 16 + l4 * 4) = o4_;      \
  } while (0)

__global__ __launch_bounds__(256, 4)
void comp6_k(const unsigned short* __restrict__ mh2, const unsigned short* __restrict__ embB,
             const unsigned* __restrict__ mbits, float* __restrict__ out) {
  __shared__ __align__(16) char lds[32768];
  int b = blockIdx.x & 255, th = blockIdx.x >> 8;
  int tid = threadIdx.x, lane = tid & 63, w = tid >> 6;
  int l15 = lane & 15, l4 = lane >> 4;
  int t = th * 64 + w * 16 + l15;

  bf16x8 fb[16];
#pragma unroll
  for (int ks = 0; ks < 16; ++ks)
    fb[ks] = *(const bf16x8*)(mh2 + (size_t)(b * 128 + t) * 512 + ks * 32 + l4 * 8);
  unsigned mw[16];
  {
    const uint4* mp = (const uint4*)(mbits + (((size_t)b * 128 + t) << 4));
    uint4 a0 = mp[0], a1 = mp[1], a2 = mp[2], a3 = mp[3];
    mw[0] = a0.x; mw[1] = a0.y; mw[2] = a0.z; mw[3] = a0.w;
    mw[4] = a1.x; mw[5] = a1.y; mw[6] = a1.z; mw[7] = a1.w;
    mw[8] = a2.x; mw[9] = a2.y; mw[10] = a2.z; mw[11] = a2.w;
    mw[12] = a3.x; mw[13] = a3.y; mw[14] = a3.z; mw[15] = a3.w;
  }

  float sum = 0.f;
  STAGEC6(0, 0);
  STAGEC6(1, 1);
  asm volatile("s_waitcnt vmcnt(4)" ::: "memory");
  __builtin_amdgcn_s_barrier();
  CCHUNK6(0);
  __builtin_amdgcn_s_barrier();
  for (int ch = 1; ch < 32; ++ch) {
    if (ch < 31) {
      STAGEC6(ch + 1, (ch + 1) & 1);
      asm volatile("s_waitcnt vmcnt(4)" ::: "memory");
    } else {
      asm volatile("s_waitcnt vmcnt(0)" ::: "memory");
    }
    __builtin_amdgcn_s_barrier();
    CCHUNK6(ch);
    __builtin_amdgcn_s_barrier();
  }

  // complete row sum (full n=512 seen by this block)
  sum += __shfl_xor(sum, 16);
  sum += __shfl_xor(sum, 32);
  float inv = 1.0f / sum;

  // drain own wave's stores (each t-row written entirely by this wave), then rescale
  asm volatile("s_waitcnt vmcnt(0)" ::: "memory");
  float4* rp = (float4*)(out + (size_t)(b * 128 + t) * 512 + l4 * 128);
#pragma unroll
  for (int i = 0; i < 32; ++i) {
    float4 v = rp[i];
    v.x *= inv; v.y *= inv; v.z *= inv; v.w *= inv;
    rp[i] = v;
  }
}

extern "C" void kernel_launch(void* const* d_in, const int* in_sizes, int n_in,
                              void* d_out, int out_size, void* d_ws, size_t ws_size,
                              hipStream_t stream) {
  (void)in_sizes; (void)n_in; (void)out_size; (void)ws_size;
  const float* emb  = (const float*)d_in[0];
  const float* mge  = (const float*)d_in[1];
  const float* cap  = (const float*)d_in[2];
  const float* Wk   = (const float*)d_in[3];
  const float* Wkt  = (const float*)d_in[4];
  const float* Wv   = (const float*)d_in[5];
  const float* Wqc  = (const float*)d_in[6];
  const float* Wqs  = (const float*)d_in[7];
  const float* Wout = (const float*)d_in[8];
  const int* prev   = (const int*)d_in[9];
  const int* mask   = (const int*)d_in[10];
  float* out = (float*)d_out;

  char* p = (char*)d_ws;
  auto take = [&](size_t n) { char* q = p; p += (n + 255) & ~(size_t)255; return q; };
  unsigned short* embB = (unsigned short*)take((size_t)131072 * 512 * 2);
  unsigned short* Kb   = (unsigned short*)take((size_t)131072 * 512 * 2);
  unsigned short* Vt   = (unsigned short*)take((size_t)131072 * 512 * 2);
  unsigned short* Qb   = (unsigned short*)take((size_t)32768 * 512 * 2);
  unsigned short* mhaB = (unsigned short*)take((size_t)32768 * 512 * 2);
  unsigned short* mh2  = (unsigned short*)take((size_t)32768 * 512 * 2);
  float*          Qc   = (float*)take((size_t)256 * 512 * 4);
  unsigned*       mbit = (unsigned*)take((size_t)256 * 128 * 16 * 4);
  unsigned short* WkT  = (unsigned short*)take(524288);
  unsigned short* WvT  = (unsigned short*)take(524288);
  unsigned short* WqsT = (unsigned short*)take(524288);
  unsigned short* WqcT = (unsigned short*)take(524288);
  unsigned short* WktB = (unsigned short*)take(524288);
  unsigned short* WoutB= (unsigned short*)take(524288);
  unsigned short* WFT  = (unsigned short*)take(524288);
  unsigned short* mgeB = (unsigned short*)take((size_t)256 * 512 * 2);

  prep_k<<<99648, 256, 0, stream>>>(emb, mask, Wkt, Wout, mge, Wk, Wv, Wqs, Wqc,
                                    embB, mbit, WktB, WoutB, mgeB, WkT, WvT, WqsT, WqcT);
  wfqc_k<<<24, 256, 0, stream>>>(WktB, WoutB, WFT, mgeB, WqcT, Qc);
  gemmq_k<<<768, 512, 0, stream>>>(embB, WqsT, Qb, Qc, Wqs + 512 * 512, cap, prev,
                                   WkT, WvT, Kb, Vt);
  attn5_k<<<2048, 512, 0, stream>>>(Qb, Kb, Vt, mbit, mhaB);
  gemm11_k<<<256, 512, 0, stream>>>(mhaB, WFT, mh2);
  comp6_k<<<512, 256, 0, stream>>>(mh2, embB, mbit, out);
}

// Round 19
// 487.023 us; speedup vs baseline: 1.0203x; 1.0203x over previous
//
#include <hip/hip_runtime.h>
#include <hip/hip_bf16.h>

// Problem constants
constexpr int Bb = 256;   // batch
constexpr int Nn = 512;   // nodes
constexpr int Dd = 512;   // model dim
constexpr int Hh = 8;     // heads
constexpr int Tt = 128;   // steps
#define NEGF (-1.0e9f)

typedef __attribute__((ext_vector_type(4))) float f32x4;
typedef __attribute__((ext_vector_type(8))) short bf16x8;     // MFMA a/b frag (8 bf16)
typedef __attribute__((ext_vector_type(8))) unsigned short u16x8;

#define AS1 __attribute__((address_space(1)))
#define AS3 __attribute__((address_space(3)))

__device__ __forceinline__ unsigned short f2bf(float f) {
  union { float f; unsigned u; } v; v.f = f;
  unsigned r = v.u + 0x7fffu + ((v.u >> 16) & 1u);   // RNE
  return (unsigned short)(r >> 16);
}

__device__ __forceinline__ unsigned cvtpk(float lo, float hi) {
  unsigned r;
  asm("v_cvt_pk_bf16_f32 %0, %1, %2" : "=v"(r) : "v"(lo), "v"(hi));
  return r;
}

__device__ __forceinline__ void cast8(const float* __restrict__ src,
                                      unsigned short* __restrict__ dst, int i) {
  const float4* s = (const float4*)src + (size_t)i * 2;
  float4 a = s[0], b = s[1];
  u16x8 o;
  o[0] = f2bf(a.x); o[1] = f2bf(a.y); o[2] = f2bf(a.z); o[3] = f2bf(a.w);
  o[4] = f2bf(b.x); o[5] = f2bf(b.y); o[6] = f2bf(b.z); o[7] = f2bf(b.w);
  ((u16x8*)dst)[i] = o;
}

// ======== prep_k: fused prologue (casts + mask bitmask + weight transpose-casts) ========
__global__ void prep_k(const float* __restrict__ emb, const int* __restrict__ mask,
                       const float* __restrict__ Wkt, const float* __restrict__ Wout,
                       const float* __restrict__ mge,
                       const float* __restrict__ Wk, const float* __restrict__ Wv,
                       const float* __restrict__ Wqs, const float* __restrict__ Wqc,
                       unsigned short* __restrict__ embB, unsigned* __restrict__ bits,
                       unsigned short* __restrict__ WktB, unsigned short* __restrict__ WoutB,
                       unsigned short* __restrict__ mgeB,
                       unsigned short* __restrict__ WkT, unsigned short* __restrict__ WvT,
                       unsigned short* __restrict__ WqsT, unsigned short* __restrict__ WqcT) {
  __shared__ float t[32][33];
  int bid = blockIdx.x, tid = threadIdx.x;
  if (bid < 32768) {
    cast8(emb, embB, bid * 256 + tid);
  } else if (bid < 98304) {
    size_t gid = (size_t)(bid - 32768) * 256 + tid;
    int mv = mask[gid];
    unsigned long long bal = __ballot(mv == 1);
    if ((tid & 63) == 0) {
      unsigned tt = (unsigned)(gid >> 17);
      unsigned b = (unsigned)((gid >> 9) & 255);
      unsigned n = (unsigned)(gid & 511);
      unsigned* dst = bits + (((size_t)b * 128 + tt) * 16 + (n >> 5));
      dst[0] = (unsigned)bal;
      dst[1] = (unsigned)(bal >> 32);
    }
  } else if (bid < 98432) {
    cast8(Wkt, WktB, (bid - 98304) * 256 + tid);
  } else if (bid < 98560) {
    cast8(Wout, WoutB, (bid - 98432) * 256 + tid);
  } else if (bid < 98624) {
    cast8(mge, mgeB, (bid - 98560) * 256 + tid);
  } else {
    int vb = bid - 98624;
    int mid = vb >> 8;
    int tile = vb & 255;
    const float* S = (mid == 0) ? Wk : (mid == 1) ? Wv : (mid == 2) ? Wqs : Wqc;
    unsigned short* Dst = (mid == 0) ? WkT : (mid == 1) ? WvT : (mid == 2) ? WqsT : WqcT;
    int r0 = (tile >> 4) * 32, c0 = (tile & 15) * 32;
    int tx = tid & 31, ty = tid >> 5;
#pragma unroll
    for (int yy = 0; yy < 4; ++yy) {
      int r = ty + yy * 8;
      t[r][tx] = S[(size_t)(r0 + r) * 512 + c0 + tx];
    }
    __syncthreads();
#pragma unroll
    for (int yy = 0; yy < 4; ++yy) {
      int c = ty + yy * 8;
      Dst[(size_t)(c0 + c) * 512 + r0 + tx] = f2bf(t[tx][c]);   // Dst[n][k] = W[k][n]
    }
  }
}

// ---------------- shared staging: 128x64 bf16 tile via global_load_lds (16B) ----------------
__device__ __forceinline__ void stage_tile(const unsigned short* __restrict__ G, int row0, int k0,
                                           unsigned short* lds_base, int wave, int lane) {
#pragma unroll
  for (int c = 0; c < 4; ++c) {
    int chunk = wave * 4 + c;                       // 16 chunks of 1KB (8 rows each)
    const unsigned short* g = G + (size_t)(row0 + chunk * 8 + (lane >> 3)) * 512 + k0 + (lane & 7) * 8;
    __builtin_amdgcn_global_load_lds((AS1 void*)g, (AS3 void*)(lds_base + chunk * 512), 16, 0, 0);
  }
}

// ======== wfqc_k: merged tiny GEMMs — blocks 0-15: WFT=WktB@WoutB^T (bf16);
//          blocks 16-23: Qc=mgeB@WqcT^T (f32) ========
__global__ __launch_bounds__(256, 2)
void wfqc_k(const unsigned short* __restrict__ A0, const unsigned short* __restrict__ BT0,
            unsigned short* __restrict__ C0,
            const unsigned short* __restrict__ A1, const unsigned short* __restrict__ BT1,
            float* __restrict__ C1) {
  __shared__ __align__(16) char lds[32768];
  unsigned short* ldsA = (unsigned short*)lds;
  unsigned short* ldsB = ldsA + 8192;
  int bid = blockIdx.x;
  bool qc = (bid >= 16);
  int lb = qc ? bid - 16 : bid;
  const unsigned short* A = qc ? A1 : A0;
  const unsigned short* BT = qc ? BT1 : BT0;
  int mt = lb >> 2, nt = lb & 3;
  int m0 = mt * 128, n0 = nt * 128;
  int tid = threadIdx.x, lane = tid & 63, w = tid >> 6;
  int wm = w >> 1, wn = w & 1;
  int l15 = lane & 15, l4 = lane >> 4;

  f32x4 acc[4][4] = {};
  for (int k0 = 0; k0 < 512; k0 += 64) {
    stage_tile(A, m0, k0, ldsA, w, lane);
    stage_tile(BT, n0, k0, ldsB, w, lane);
    __syncthreads();
#pragma unroll
    for (int ks = 0; ks < 2; ++ks) {
      bf16x8 fa[4], fb[4];
#pragma unroll
      for (int ii = 0; ii < 4; ++ii)
        fa[ii] = *(const bf16x8*)(ldsA + (wm * 64 + ii * 16 + l15) * 64 + ks * 32 + l4 * 8);
#pragma unroll
      for (int jj = 0; jj < 4; ++jj)
        fb[jj] = *(const bf16x8*)(ldsB + (wn * 64 + jj * 16 + l15) * 64 + ks * 32 + l4 * 8);
#pragma unroll
      for (int ii = 0; ii < 4; ++ii)
#pragma unroll
        for (int jj = 0; jj < 4; ++jj)
          acc[ii][jj] = __builtin_amdgcn_mfma_f32_16x16x32_bf16(fa[ii], fb[jj], acc[ii][jj], 0, 0, 0);
    }
    __syncthreads();
  }
#pragma unroll
  for (int ii = 0; ii < 4; ++ii)
#pragma unroll
    for (int jj = 0; jj < 4; ++jj)
#pragma unroll
      for (int r = 0; r < 4; ++r) {
        int row = m0 + wm * 64 + ii * 16 + l4 * 4 + r;
        int col = n0 + wn * 64 + jj * 16 + l15;
        if (qc) C1[(size_t)row * 512 + col] = acc[ii][jj][r];
        else C0[(size_t)row * 512 + col] = f2bf(acc[ii][jj][r]);
      }
}

// ---------------- shared 8-phase macros (proven in gemm8f/gemm10/gemm11) ----------------
#define LDA_Q(QM)                                                   \
  _Pragma("unroll")                                                 \
  for (int ii = 0; ii < 4; ++ii) {                                  \
    int rr_ = (QM) * 64 + ii * 16 + l15;                            \
    const char* ap_ = ldsAh + rr_ * 128;                            \
    int sw_ = (rr_ & 7) << 4;                                       \
    fa[ii][0] = *(const bf16x8*)(ap_ + ((l4 * 16) ^ sw_));          \
    fa[ii][1] = *(const bf16x8*)(ap_ + ((64 + l4 * 16) ^ sw_));     \
  }

#define LDB_Q(QN)                                                   \
  _Pragma("unroll")                                                 \
  for (int jj = 0; jj < 2; ++jj) {                                  \
    int rr_ = (wn & 1) * 64 + (QN) * 32 + jj * 16 + l15;            \
    const char* bp_ = ldsBh + rr_ * 128;                            \
    int sw_ = (rr_ & 7) << 4;                                       \
    fb[jj][0] = *(const bf16x8*)(bp_ + ((l4 * 16) ^ sw_));          \
    fb[jj][1] = *(const bf16x8*)(bp_ + ((64 + l4 * 16) ^ sw_));     \
  }

#define MM16(QM, QN)                                                              \
  do {                                                                            \
    __builtin_amdgcn_s_setprio(1);                                                \
    _Pragma("unroll")                                                             \
    for (int ii = 0; ii < 4; ++ii)                                                \
      _Pragma("unroll")                                                           \
      for (int jj = 0; jj < 2; ++jj) {                                            \
        acc[(QM) * 4 + ii][(QN) * 2 + jj] = __builtin_amdgcn_mfma_f32_16x16x32_bf16( \
            fa[ii][0], fb[jj][0], acc[(QM) * 4 + ii][(QN) * 2 + jj], 0, 0, 0);    \
        acc[(QM) * 4 + ii][(QN) * 2 + jj] = __builtin_amdgcn_mfma_f32_16x16x32_bf16( \
            fa[ii][1], fb[jj][1], acc[(QM) * 4 + ii][(QN) * 2 + jj], 0, 0, 0);    \
      }                                                                           \
    __builtin_amdgcn_s_setprio(0);                                                \
  } while (0)

// gemm10 staging (persistent double GEMM part)
#define STAGE10A(SLOT, H, ROWB, KT)                                               \
  do {                                                                             \
    int rb_ = (ROWB) + (H) * 128;                                                  \
    char* Lb_ = lds + (SLOT) * 32768 + (H) * 16384;                                \
    _Pragma("unroll")                                                              \
    for (int sh_ = 0; sh_ < 2; ++sh_) {                                            \
      int off_ = sh_ * 8192 + tid * 16;                                            \
      int r_ = off_ >> 7;                                                          \
      int c_ = (off_ & 127) ^ ((r_ & 7) << 4);                                     \
      const char* g_ = (const char*)(A + (size_t)(rb_ + r_) * 512 + (KT) * 64) + c_; \
      __builtin_amdgcn_global_load_lds((AS1 void*)g_, (AS3 void*)(Lb_ + off_), 16, 0, 0); \
    }                                                                              \
  } while (0)

#define STAGE10B(SLOT, H, KT)                                                      \
  do {                                                                             \
    int rb_ = n0 + (H) * 128;                                                      \
    char* Lb_ = lds + 98304 + (SLOT) * 32768 + (H) * 16384;                        \
    _Pragma("unroll")                                                              \
    for (int sh_ = 0; sh_ < 2; ++sh_) {                                            \
      int off_ = sh_ * 8192 + tid * 16;                                            \
      int r_ = off_ >> 7;                                                          \
      int c_ = (off_ & 127) ^ ((r_ & 7) << 4);                                     \
      const char* g_ = (const char*)(BT + (size_t)(rb_ + r_) * 512 + (KT) * 64) + c_; \
      __builtin_amdgcn_global_load_lds((AS1 void*)g_, (AS3 void*)(Lb_ + off_), 16, 0, 0); \
    }                                                                              \
  } while (0)

// gemm11 staging (single-tile q/mh2 part; A via per-thread bases, supports gather)
#define STAGE11A(SLOT, H, KT)                                                      \
  do {                                                                             \
    char* Lb_ = lds + (SLOT) * 65536 + (H) * 16384;                                \
    __builtin_amdgcn_global_load_lds((AS1 void*)(abase[(H) * 2 + 0] + (KT) * 128), \
        (AS3 void*)(Lb_ + tid * 16), 16, 0, 0);                                    \
    __builtin_amdgcn_global_load_lds((AS1 void*)(abase[(H) * 2 + 1] + (KT) * 128), \
        (AS3 void*)(Lb_ + 8192 + tid * 16), 16, 0, 0);                             \
  } while (0)

#define STAGE11B(SLOT, H, KT)                                                      \
  do {                                                                             \
    int rb_ = n0 + (H) * 128;                                                      \
    char* Lb_ = lds + (SLOT) * 65536 + 32768 + (H) * 16384;                        \
    _Pragma("unroll")                                                              \
    for (int sh_ = 0; sh_ < 2; ++sh_) {                                            \
      int off_ = sh_ * 8192 + tid * 16;                                            \
      int r_ = off_ >> 7;                                                          \
      int c_ = (off_ & 127) ^ ((r_ & 7) << 4);                                     \
      const char* g_ = (const char*)(BT + (size_t)(rb_ + r_) * 512 + (KT) * 64) + c_; \
      __builtin_amdgcn_global_load_lds((AS1 void*)g_, (AS3 void*)(Lb_ + off_), 16, 0, 0); \
    }                                                                              \
  } while (0)

// ======== gemmq_k: FUSED dispatch. blocks [0,256): gemm11<3> (Qb, gathered A).
//          blocks [256,768): gemm10 persistent double GEMM (Kb + Vt). ========
__global__ __launch_bounds__(512, 1)
void gemmq_k(const unsigned short* __restrict__ embB,
             const unsigned short* __restrict__ WqsT,
             unsigned short* __restrict__ Qb,
             const float* __restrict__ Qc, const float* __restrict__ WqsL,
             const float* __restrict__ capp, const int* __restrict__ prev,
             const unsigned short* __restrict__ B0, const unsigned short* __restrict__ B1,
             unsigned short* __restrict__ C0, unsigned short* __restrict__ C2) {
  __shared__ __align__(16) char lds[163840];
  int tid = threadIdx.x, lane = tid & 63, w = tid >> 6;
  int l15 = lane & 15, l4 = lane >> 4;

  if (blockIdx.x < 256) {
    // ---------------- gemm11<3>: Qb projection with gathered A rows ----------------
    const unsigned short* A = embB;
    const unsigned short* BT = WqsT;
    int xcd = blockIdx.x & 7, loc = blockIdx.x >> 3;   // loc < 32
    int mt = xcd * 16 + (loc >> 1), nh = loc & 1;
    int m0 = mt * 256, n0 = nh * 256;
    int wm = w >> 2, wn = w & 3;

    const char* abase[4];
#pragma unroll
    for (int hs = 0; hs < 4; ++hs) {
      int H = hs >> 1, sh = hs & 1;
      int off = sh * 8192 + tid * 16;
      int r = off >> 7;
      int c = (off & 127) ^ ((r & 7) << 4);
      int row = m0 + H * 128 + r;
      int t = row >> 8, bb = row & 255;
      int pa = prev[t * Bb + bb];
      abase[hs] = (const char*)(A + (size_t)(bb * 512 + pa) * 512) + c;
    }

    f32x4 acc[8][4] = {};
    bf16x8 fa[4][2], fb[2][2];

    STAGE11A(0, 0, 0); STAGE11A(0, 1, 0);
    STAGE11B(0, 0, 0); STAGE11B(0, 1, 0);

    for (int kt = 0; kt < 8; ++kt) {
      int s = kt & 1, sn = s ^ 1;
      char* ldsAh = lds + s * 65536 + wm * 16384;
      char* ldsBh = lds + s * 65536 + 32768 + (wn >> 1) * 16384;
      if (kt < 7) {
        STAGE11A(sn, 0, kt + 1);
        asm volatile("s_waitcnt vmcnt(2)" ::: "memory");
      } else {
        asm volatile("s_waitcnt vmcnt(0)" ::: "memory");
      }
      __builtin_amdgcn_s_barrier();
      LDA_Q(0); LDB_Q(0);
      MM16(0, 0);
      __builtin_amdgcn_s_barrier();
      LDB_Q(1);
      if (kt < 7) STAGE11A(sn, 1, kt + 1);
      __builtin_amdgcn_s_barrier();
      MM16(0, 1);
      __builtin_amdgcn_s_barrier();
      LDA_Q(1);
      if (kt < 7) STAGE11B(sn, 0, kt + 1);
      __builtin_amdgcn_s_barrier();
      MM16(1, 1);
      __builtin_amdgcn_s_barrier();
      LDB_Q(0);
      if (kt < 7) STAGE11B(sn, 1, kt + 1);
      __builtin_amdgcn_s_barrier();
      MM16(1, 0);
      __builtin_amdgcn_s_barrier();
    }

#pragma unroll
    for (int mi = 0; mi < 8; ++mi)
#pragma unroll
      for (int nj = 0; nj < 4; ++nj)
#pragma unroll
        for (int r = 0; r < 4; ++r) {
          int row = m0 + wm * 128 + mi * 16 + l4 * 4 + r;
          int col = n0 + wn * 64 + nj * 16 + l15;
          int t = row >> 8, bbx = row & 255;
          float val = acc[mi][nj][r] + Qc[(size_t)bbx * 512 + col] + (1.0f - capp[row]) * WqsL[col];
          Qb[(size_t)(bbx * 128 + t) * 512 + col] = f2bf(val * 0.125f);
        }
  } else {
    // ---------------- gemm10: persistent 4-tile fused double GEMM (K / V^T) ----------------
    const unsigned short* A = embB;
    int bid = blockIdx.x - 256;
    int xcd = bid & 7, loc = bid >> 3;   // loc < 64
    int ml4 = loc >> 2, cmb = loc & 3;
    int grp = cmb >> 1, nh = cmb & 1;
    const unsigned short* BT = grp ? B1 : B0;
    int mtb = xcd * 64 + ml4 * 4;
    int n0 = nh * 256;
    int wm = w >> 2, wn = w & 3;

    f32x4 acc[8][4] = {};
    bf16x8 fa[4][2], fb[2][2];

    {
      int m00 = mtb * 256;
      STAGE10A(0, 0, m00, 0); STAGE10A(0, 1, m00, 0);
      STAGE10A(1, 0, m00, 1); STAGE10A(1, 1, m00, 1);
      STAGE10B(0, 0, 0);      STAGE10B(0, 1, 0);
    }

    for (int g = 0; g < 32; ++g) {
      int As = g % 3, Astg = (g + 2) % 3;
      int Bs = g & 1, Bstg = Bs ^ 1;
      char* ldsAh = lds + As * 32768 + wm * 16384;
      char* ldsBh = lds + 98304 + Bs * 32768 + (wn >> 1) * 16384;
      int g2 = g + 2;
      int m0A = (mtb + (g2 >> 3)) * 256, ktA = g2 & 7;
      int ktB = (g + 1) & 7;
      if (g < 30) {
        STAGE10A(Astg, 0, m0A, ktA);
        asm volatile("s_waitcnt vmcnt(2)" ::: "memory");
      } else {
        asm volatile("s_waitcnt vmcnt(0)" ::: "memory");
      }
      __builtin_amdgcn_s_barrier();
      LDA_Q(0); LDB_Q(0);
      MM16(0, 0);
      __builtin_amdgcn_s_barrier();
      LDB_Q(1);
      if (g < 30) STAGE10A(Astg, 1, m0A, ktA);
      __builtin_amdgcn_s_barrier();
      MM16(0, 1);
      __builtin_amdgcn_s_barrier();
      LDA_Q(1);
      if (g < 31) STAGE10B(Bstg, 0, ktB);
      __builtin_amdgcn_s_barrier();
      MM16(1, 1);
      __builtin_amdgcn_s_barrier();
      LDB_Q(0);
      if (g < 31) STAGE10B(Bstg, 1, ktB);
      __builtin_amdgcn_s_barrier();
      MM16(1, 0);
      __builtin_amdgcn_s_barrier();

      if ((g & 7) == 7) {
        int m0cur = (mtb + (g >> 3)) * 256;
        if (grp == 0) {
#pragma unroll
          for (int mi = 0; mi < 8; ++mi)
#pragma unroll
            for (int nj = 0; nj < 4; ++nj)
#pragma unroll
              for (int r = 0; r < 4; ++r) {
                int row = m0cur + wm * 128 + mi * 16 + l4 * 4 + r;
                int col = n0 + wn * 64 + nj * 16 + l15;
                C0[(size_t)row * 512 + col] = f2bf(acc[mi][nj][r]);
              }
        } else {
          int bb = m0cur >> 9, nn0 = m0cur & 511;
          char* wb = lds + As * 32768 + w * 4096;
          int rdrow = lane >> 3, nseg = lane & 7;
#pragma unroll
          for (int p = 0; p < 8; ++p) {
            int nj = p >> 1;
            if ((l15 >> 3) == (p & 1)) {
              int rowL = l15 & 7;
#pragma unroll
              for (int mi = 0; mi < 8; ++mi) {
                ushort4 w4;
                w4.x = f2bf(acc[mi][nj][0]);
                w4.y = f2bf(acc[mi][nj][1]);
                w4.z = f2bf(acc[mi][nj][2]);
                w4.w = f2bf(acc[mi][nj][3]);
                *(ushort4*)(wb + rowL * 272 + (mi * 16 + l4 * 4) * 2) = w4;
              }
            }
            asm volatile("s_waitcnt lgkmcnt(0)" ::: "memory");
            u16x8 v0 = *(const u16x8*)(wb + rdrow * 272 + nseg * 16);
            u16x8 v1 = *(const u16x8*)(wb + rdrow * 272 + 128 + nseg * 16);
            int dglob = n0 + wn * 64 + p * 8 + rdrow;
            unsigned short* dp = C2 + (size_t)(bb * 512 + dglob) * 512 + nn0 + wm * 128;
            *(u16x8*)(dp + nseg * 8) = v0;
            *(u16x8*)(dp + 64 + nseg * 8) = v1;
            asm volatile("s_waitcnt lgkmcnt(0)" ::: "memory");
          }
        }
#pragma unroll
        for (int mi = 0; mi < 8; ++mi)
#pragma unroll
          for (int nj = 0; nj < 4; ++nj)
            acc[mi][nj] = (f32x4){0.f, 0.f, 0.f, 0.f};
        __syncthreads();
      }
    }
  }
}

// ======== gemm11<1>: 256x256 8-phase single-tile GEMM (mh2 = mhaB @ WFT^T) ========
__global__ __launch_bounds__(512, 1)
void gemm11_k(const unsigned short* __restrict__ A, const unsigned short* __restrict__ BT,
              unsigned short* __restrict__ C) {
  __shared__ __align__(16) char lds[131072];
  int xcd = blockIdx.x & 7, loc = blockIdx.x >> 3;   // loc < 32
  int mt = xcd * 16 + (loc >> 1), nh = loc & 1;
  int m0 = mt * 256, n0 = nh * 256;
  int tid = threadIdx.x, lane = tid & 63, w = tid >> 6;
  int wm = w >> 2, wn = w & 3;
  int l15 = lane & 15, l4 = lane >> 4;

  const char* abase[4];
#pragma unroll
  for (int hs = 0; hs < 4; ++hs) {
    int H = hs >> 1, sh = hs & 1;
    int off = sh * 8192 + tid * 16;
    int r = off >> 7;
    int c = (off & 127) ^ ((r & 7) << 4);
    int row = m0 + H * 128 + r;
    abase[hs] = (const char*)(A + (size_t)row * 512) + c;
  }

  f32x4 acc[8][4] = {};
  bf16x8 fa[4][2], fb[2][2];

  STAGE11A(0, 0, 0); STAGE11A(0, 1, 0);
  STAGE11B(0, 0, 0); STAGE11B(0, 1, 0);

  for (int kt = 0; kt < 8; ++kt) {
    int s = kt & 1, sn = s ^ 1;
    char* ldsAh = lds + s * 65536 + wm * 16384;
    char* ldsBh = lds + s * 65536 + 32768 + (wn >> 1) * 16384;
    if (kt < 7) {
      STAGE11A(sn, 0, kt + 1);
      asm volatile("s_waitcnt vmcnt(2)" ::: "memory");
    } else {
      asm volatile("s_waitcnt vmcnt(0)" ::: "memory");
    }
    __builtin_amdgcn_s_barrier();
    LDA_Q(0); LDB_Q(0);
    MM16(0, 0);
    __builtin_amdgcn_s_barrier();
    LDB_Q(1);
    if (kt < 7) STAGE11A(sn, 1, kt + 1);
    __builtin_amdgcn_s_barrier();
    MM16(0, 1);
    __builtin_amdgcn_s_barrier();
    LDA_Q(1);
    if (kt < 7) STAGE11B(sn, 0, kt + 1);
    __builtin_amdgcn_s_barrier();
    MM16(1, 1);
    __builtin_amdgcn_s_barrier();
    LDB_Q(0);
    if (kt < 7) STAGE11B(sn, 1, kt + 1);
    __builtin_amdgcn_s_barrier();
    MM16(1, 0);
    __builtin_amdgcn_s_barrier();
  }

#pragma unroll
  for (int mi = 0; mi < 8; ++mi)
#pragma unroll
    for (int nj = 0; nj < 4; ++nj)
#pragma unroll
      for (int r = 0; r < 4; ++r) {
        int row = m0 + wm * 128 + mi * 16 + l4 * 4 + r;
        int col = n0 + wn * 64 + nj * 16 + l15;
        C[(size_t)row * 512 + col] = f2bf(acc[mi][nj][r]);
      }
}

// ================= attn5: LDS-staged chunked flash pipeline =================
#define STAGEK5(CH, SLOT)                                                          \
  do {                                                                             \
    _Pragma("unroll")                                                              \
    for (int sh_ = 0; sh_ < 2; ++sh_) {                                            \
      int off_ = sh_ * 8192 + tid * 16;                                            \
      int r_ = off_ >> 7;                                                          \
      int c_ = (off_ & 127) ^ ((r_ & 7) << 4);                                     \
      const char* g_ = (const char*)(Kb + (size_t)(b * 512 + (CH) * 128 + r_) * 512 + h * 64) + c_; \
      __builtin_amdgcn_global_load_lds((AS1 void*)g_, (AS3 void*)(lds + (SLOT) * 16384 + off_), 16, 0, 0); \
    }                                                                              \
  } while (0)

#define STAGEV5(CH, SLOT)                                                          \
  do {                                                                             \
    _Pragma("unroll")                                                              \
    for (int sh_ = 0; sh_ < 2; ++sh_) {                                            \
      int off_ = sh_ * 8192 + tid * 16;                                            \
      int r_ = off_ >> 8;                                                          \
      int c_ = (off_ & 255) ^ ((r_ & 7) << 4);                                     \
      const char* g_ = (const char*)(Vt + (size_t)(b * 512 + h * 64 + r_) * 512 + (CH) * 128) + c_; \
      __builtin_amdgcn_global_load_lds((AS1 void*)g_, (AS3 void*)(lds + 32768 + (SLOT) * 16384 + off_), 16, 0, 0); \
    }                                                                              \
  } while (0)

#define CHUNK5(CH)                                                                 \
  do {                                                                             \
    const char* Ks_ = lds + ((CH) & 1) * 16384;                                    \
    const char* Vs_ = lds + 32768 + ((CH) & 1) * 16384;                            \
    f32x4 sck[8];                                                                  \
    _Pragma("unroll")                                                              \
    for (int jj = 0; jj < 8; ++jj) sck[jj] = (f32x4){0.f, 0.f, 0.f, 0.f};          \
    _Pragma("unroll")                                                              \
    for (int jj = 0; jj < 8; ++jj) {                                               \
      int rr_ = jj * 16 + l15;                                                     \
      int sw_ = (rr_ & 7) << 4;                                                    \
      bf16x8 k0_ = *(const bf16x8*)(Ks_ + rr_ * 128 + ((l4 * 16) ^ sw_));          \
      bf16x8 k1_ = *(const bf16x8*)(Ks_ + rr_ * 128 + ((64 + l4 * 16) ^ sw_));     \
      sck[jj] = __builtin_amdgcn_mfma_f32_16x16x32_bf16(k0_, fq[0], sck[jj], 0, 0, 0); \
      sck[jj] = __builtin_amdgcn_mfma_f32_16x16x32_bf16(k1_, fq[1], sck[jj], 0, 0, 0); \
    }                                                                              \
    unsigned mwarr_[4] = {mqs[CH].x, mqs[CH].y, mqs[CH].z, mqs[CH].w};             \
    float cmx_ = -3.0e38f;                                                         \
    _Pragma("unroll")                                                              \
    for (int jj = 0; jj < 8; ++jj) {                                               \
      unsigned nib_ = mwarr_[jj >> 1] >> (((jj & 1) << 4) + (l4 << 2));            \
      _Pragma("unroll")                                                            \
      for (int r = 0; r < 4; ++r)                                                  \
        sck[jj][r] = ((nib_ >> r) & 1) ? NEGF : sck[jj][r];                        \
      float m01_ = fmaxf(sck[jj][0], sck[jj][1]);                                  \
      float m23_ = fmaxf(sck[jj][2], sck[jj][3]);                                  \
      cmx_ = fmaxf(cmx_, fmaxf(m01_, m23_));                                       \
    }                                                                              \
    cmx_ = fmaxf(cmx_, __shfl_xor(cmx_, 16));                                      \
    cmx_ = fmaxf(cmx_, __shfl_xor(cmx_, 32));                                      \
    float mn_ = fmaxf(mx, cmx_);                                                   \
    float al_ = __expf(mx - mn_);                                                  \
    sum *= al_;                                                                    \
    _Pragma("unroll")                                                              \
    for (int dj = 0; dj < 4; ++dj)                                                 \
      _Pragma("unroll")                                                            \
      for (int r = 0; r < 4; ++r) o[dj][r] *= al_;                                 \
    mx = mn_;                                                                      \
    _Pragma("unroll")                                                              \
    for (int jj = 0; jj < 8; ++jj) {                                               \
      _Pragma("unroll")                                                            \
      for (int r = 0; r < 4; ++r) sck[jj][r] = __expf(sck[jj][r] - mx);            \
      sum += (sck[jj][0] + sck[jj][1]) + (sck[jj][2] + sck[jj][3]);                \
    }                                                                              \
    _Pragma("unroll")                                                              \
    for (int g = 0; g < 4; ++g) {                                                  \
      unsigned a0_ = cvtpk(sck[2 * g][0], sck[2 * g][1]);                          \
      unsigned a1_ = cvtpk(sck[2 * g][2], sck[2 * g][3]);                          \
      unsigned b0_ = cvtpk(sck[2 * g + 1][0], sck[2 * g + 1][1]);                  \
      unsigned b1_ = cvtpk(sck[2 * g + 1][2], sck[2 * g + 1][3]);                  \
      unsigned wA0_ = __shfl(a0_, src0, 64), wB0_ = __shfl(b0_, src0, 64);         \
      unsigned wA1_ = __shfl(a1_, src0, 64), wB1_ = __shfl(b1_, src0, 64);         \
      unsigned wA2_ = __shfl(a0_, src2, 64), wB2_ = __shfl(b0_, src2, 64);         \
      unsigned wA3_ = __shfl(a1_, src2, 64), wB3_ = __shfl(b1_, src2, 64);         \
      union { unsigned u[4]; bf16x8 v; } pu_;                                      \
      pu_.u[0] = loh ? wA0_ : wB0_;                                                \
      pu_.u[1] = loh ? wA1_ : wB1_;                                                \
      pu_.u[2] = loh ? wA2_ : wB2_;                                                \
      pu_.u[3] = loh ? wA3_ : wB3_;                                                \
      _Pragma("unroll")                                                            \
      for (int dj = 0; dj < 4; ++dj) {                                             \
        int rr_ = dj * 16 + l15;                                                   \
        int sw_ = (rr_ & 7) << 4;                                                  \
        bf16x8 fv_ = *(const bf16x8*)(Vs_ + rr_ * 256 + ((g * 64 + l4 * 16) ^ sw_)); \
        o[dj] = __builtin_amdgcn_mfma_f32_16x16x32_bf16(fv_, pu_.v, o[dj], 0, 0, 0); \
      }                                                                            \
    }                                                                              \
  } while (0)

__global__ __launch_bounds__(512, 4)
void attn5_k(const unsigned short* __restrict__ Qb, const unsigned short* __restrict__ Kb,
             const unsigned short* __restrict__ Vt, const unsigned* __restrict__ mbits,
             unsigned short* __restrict__ mhaB) {
  __shared__ __align__(16) char lds[65536];
  int bid = blockIdx.x;
  int h = bid & 7, b = bid >> 3;
  int tid = threadIdx.x, lane = tid & 63, w = tid >> 6;
  int l15 = lane & 15, l4 = lane >> 4;
  int t = w * 16 + l15;

  bf16x8 fq[2];
#pragma unroll
  for (int ks = 0; ks < 2; ++ks)
    fq[ks] = *(const bf16x8*)(Qb + (size_t)(b * 128 + t) * 512 + h * 64 + ks * 32 + l4 * 8);
  uint4 mqs[4];
  {
    const uint4* mp = (const uint4*)(mbits + (((size_t)b * 128 + t) << 4));
    mqs[0] = mp[0]; mqs[1] = mp[1]; mqs[2] = mp[2]; mqs[3] = mp[3];
  }

  float mx = -3.0e38f, sum = 0.f;
  f32x4 o[4] = {};
  int src0 = l15 + ((l4 & 1) ? 32 : 0);
  int src2 = l15 + ((l4 & 1) ? 48 : 16);
  bool loh = (l4 < 2);

  STAGEK5(0, 0); STAGEV5(0, 0);
  STAGEK5(1, 1); STAGEV5(1, 1);
  asm volatile("s_waitcnt vmcnt(4)" ::: "memory");
  __builtin_amdgcn_s_barrier();
  CHUNK5(0);
  __builtin_amdgcn_s_barrier();
  STAGEK5(2, 0); STAGEV5(2, 0);
  asm volatile("s_waitcnt vmcnt(4)" ::: "memory");
  __builtin_amdgcn_s_barrier();
  CHUNK5(1);
  __builtin_amdgcn_s_barrier();
  STAGEK5(3, 1); STAGEV5(3, 1);
  asm volatile("s_waitcnt vmcnt(4)" ::: "memory");
  __builtin_amdgcn_s_barrier();
  CHUNK5(2);
  __builtin_amdgcn_s_barrier();
  asm volatile("s_waitcnt vmcnt(0)" ::: "memory");
  __builtin_amdgcn_s_barrier();
  CHUNK5(3);

  sum += __shfl_xor(sum, 16);
  sum += __shfl_xor(sum, 32);
  float inv = 1.0f / sum;
#pragma unroll
  for (int dj = 0; dj < 4; ++dj) {
    ushort4 w4;
    w4.x = f2bf(o[dj][0] * inv);
    w4.y = f2bf(o[dj][1] * inv);
    w4.z = f2bf(o[dj][2] * inv);
    w4.w = f2bf(o[dj][3] * inv);
    *(ushort4*)(mhaB + (size_t)(b * 128 + t) * 512 + h * 64 + dj * 16 + l4 * 4) = w4;
  }
}

// ========= comp5: n-split (b, nh) pointer logits, 32-row chunks, 2 blocks/CU =========
#define STAGEC5(CH, SLOT)                                                          \
  do {                                                                             \
    _Pragma("unroll")                                                              \
    for (int ps_ = 0; ps_ < 4; ++ps_) {                                            \
      int off_ = ps_ * 8192 + tid * 16;                                            \
      int r_ = off_ >> 10;                                                         \
      int c_ = (off_ & 1023) ^ ((r_ & 7) << 4);                                    \
      const char* g_ = (const char*)(embB + (size_t)(b * 512 + nh * 256 + (CH) * 32 + r_) * 512) + c_; \
      __builtin_amdgcn_global_load_lds((AS1 void*)g_, (AS3 void*)(lds + (SLOT) * 32768 + off_), 16, 0, 0); \
    }                                                                              \
  } while (0)

#define CCHUNK5(CH)                                                                \
  do {                                                                             \
    const char* Es_ = lds + ((CH) & 1) * 32768;                                    \
    _Pragma("unroll")                                                              \
    for (int jjl_ = 0; jjl_ < 2; ++jjl_) {                                         \
      f32x4 sck = (f32x4){0.f, 0.f, 0.f, 0.f};                                     \
      int rr_ = jjl_ * 16 + l15;                                                   \
      const char* ep_ = Es_ + rr_ * 1024;                                          \
      int sw_ = (rr_ & 7) << 4;                                                    \
      _Pragma("unroll")                                                            \
      for (int ks_ = 0; ks_ < 16; ++ks_) {                                         \
        bf16x8 fa_ = *(const bf16x8*)(ep_ + ((ks_ * 64 + l4 * 16) ^ sw_));         \
        sck = __builtin_amdgcn_mfma_f32_16x16x32_bf16(fa_, fb[ks_], sck, 0, 0, 0); \
      }                                                                            \
      unsigned nib_ = mwh[CH] >> ((jjl_ << 4) + (l4 << 2));                        \
      float4 o4_;                                                                  \
      float* po_ = (float*)&o4_;                                                   \
      _Pragma("unroll")                                                            \
      for (int r = 0; r < 4; ++r) {                                                \
        float y_ = sck[r] * 0.044194173824159216f;                                 \
        y_ = fminf(fmaxf(y_, -15.f), 15.f);                                        \
        float e2_ = __expf(2.f * y_);                                              \
        float th_ = (e2_ - 1.f) / (e2_ + 1.f);                                     \
        float p_ = __expf(th_ * 10.f - 10.f);                                      \
        p_ = ((nib_ >> r) & 1) ? 0.f : p_;                                         \
        po_[r] = p_;                                                               \
        sum += p_;                                                                 \
      }                                                                            \
      *(float4*)(out + (size_t)(b * 128 + t) * 512 + nh * 256 + (CH) * 32 + jjl_ * 16 + l4 * 4) = o4_; \
    }                                                                              \
  } while (0)

__global__ __launch_bounds__(512, 2)
void comp5_k(const unsigned short* __restrict__ mh2, const unsigned short* __restrict__ embB,
             const unsigned* __restrict__ mbits, float* __restrict__ out,
             float* __restrict__ sums) {
  __shared__ __align__(16) char lds[65536];
  int b = blockIdx.x >> 1, nh = blockIdx.x & 1;
  int tid = threadIdx.x, lane = tid & 63, w = tid >> 6;
  int l15 = lane & 15, l4 = lane >> 4;
  int t = w * 16 + l15;

  bf16x8 fb[16];
#pragma unroll
  for (int ks = 0; ks < 16; ++ks)
    fb[ks] = *(const bf16x8*)(mh2 + (size_t)(b * 128 + t) * 512 + ks * 32 + l4 * 8);
  unsigned mwh[8];
  {
    const uint4* mp = (const uint4*)(mbits + (((size_t)b * 128 + t) << 4)) + nh * 2;
    uint4 a0 = mp[0], a1 = mp[1];
    mwh[0] = a0.x; mwh[1] = a0.y; mwh[2] = a0.z; mwh[3] = a0.w;
    mwh[4] = a1.x; mwh[5] = a1.y; mwh[6] = a1.z; mwh[7] = a1.w;
  }

  float sum = 0.f;
  STAGEC5(0, 0);
  STAGEC5(1, 1);
  asm volatile("s_waitcnt vmcnt(4)" ::: "memory");
  __builtin_amdgcn_s_barrier();
  CCHUNK5(0);
  __builtin_amdgcn_s_barrier();
  STAGEC5(2, 0);
  asm volatile("s_waitcnt vmcnt(4)" ::: "memory");
  __builtin_amdgcn_s_barrier();
  CCHUNK5(1);
  __builtin_amdgcn_s_barrier();
  STAGEC5(3, 1);
  asm volatile("s_waitcnt vmcnt(4)" ::: "memory");
  __builtin_amdgcn_s_barrier();
  CCHUNK5(2);
  __builtin_amdgcn_s_barrier();
  STAGEC5(4, 0);
  asm volatile("s_waitcnt vmcnt(4)" ::: "memory");
  __builtin_amdgcn_s_barrier();
  CCHUNK5(3);
  __builtin_amdgcn_s_barrier();
  STAGEC5(5, 1);
  asm volatile("s_waitcnt vmcnt(4)" ::: "memory");
  __builtin_amdgcn_s_barrier();
  CCHUNK5(4);
  __builtin_amdgcn_s_barrier();
  STAGEC5(6, 0);
  asm volatile("s_waitcnt vmcnt(4)" ::: "memory");
  __builtin_amdgcn_s_barrier();
  CCHUNK5(5);
  __builtin_amdgcn_s_barrier();
  STAGEC5(7, 1);
  asm volatile("s_waitcnt vmcnt(4)" ::: "memory");
  __builtin_amdgcn_s_barrier();
  CCHUNK5(6);
  __builtin_amdgcn_s_barrier();
  asm volatile("s_waitcnt vmcnt(0)" ::: "memory");
  __builtin_amdgcn_s_barrier();
  CCHUNK5(7);

  sum += __shfl_xor(sum, 16);
  sum += __shfl_xor(sum, 32);
  if (l4 == 0) sums[nh * 32768 + b * 128 + t] = sum;
}

// ---------------- normalize: out[row][:] *= 1/(s0[row]+s1[row]) ----------------
__global__ void norm_k(float* __restrict__ out, const float* __restrict__ sums) {
  int row = blockIdx.x * 4 + (threadIdx.x >> 6);
  int lane = threadIdx.x & 63;
  float inv = 1.0f / (sums[row] + sums[32768 + row]);
  float4* p = (float4*)(out + (size_t)row * 512) + lane;
  float4 a = p[0], b = p[64];
  a.x *= inv; a.y *= inv; a.z *= inv; a.w *= inv;
  b.x *= inv; b.y *= inv; b.z *= inv; b.w *= inv;
  p[0] = a; p[64] = b;
}

extern "C" void kernel_launch(void* const* d_in, const int* in_sizes, int n_in,
                              void* d_out, int out_size, void* d_ws, size_t ws_size,
                              hipStream_t stream) {
  (void)in_sizes; (void)n_in; (void)out_size; (void)ws_size;
  const float* emb  = (const float*)d_in[0];
  const float* mge  = (const float*)d_in[1];
  const float* cap  = (const float*)d_in[2];
  const float* Wk   = (const float*)d_in[3];
  const float* Wkt  = (const float*)d_in[4];
  const float* Wv   = (const float*)d_in[5];
  const float* Wqc  = (const float*)d_in[6];
  const float* Wqs  = (const float*)d_in[7];
  const float* Wout = (const float*)d_in[8];
  const int* prev   = (const int*)d_in[9];
  const int* mask   = (const int*)d_in[10];
  float* out = (float*)d_out;

  char* p = (char*)d_ws;
  auto take = [&](size_t n) { char* q = p; p += (n + 255) & ~(size_t)255; return q; };
  unsigned short* embB = (unsigned short*)take((size_t)131072 * 512 * 2);
  unsigned short* Kb   = (unsigned short*)take((size_t)131072 * 512 * 2);
  unsigned short* Vt   = (unsigned short*)take((size_t)131072 * 512 * 2);
  unsigned short* Qb   = (unsigned short*)take((size_t)32768 * 512 * 2);
  unsigned short* mhaB = (unsigned short*)take((size_t)32768 * 512 * 2);
  unsigned short* mh2  = (unsigned short*)take((size_t)32768 * 512 * 2);
  float*          Qc   = (float*)take((size_t)256 * 512 * 4);
  unsigned*       mbit = (unsigned*)take((size_t)256 * 128 * 16 * 4);
  float*          sums = (float*)take((size_t)2 * 32768 * 4);
  unsigned short* WkT  = (unsigned short*)take(524288);
  unsigned short* WvT  = (unsigned short*)take(524288);
  unsigned short* WqsT = (unsigned short*)take(524288);
  unsigned short* WqcT = (unsigned short*)take(524288);
  unsigned short* WktB = (unsigned short*)take(524288);
  unsigned short* WoutB= (unsigned short*)take(524288);
  unsigned short* WFT  = (unsigned short*)take(524288);
  unsigned short* mgeB = (unsigned short*)take((size_t)256 * 512 * 2);

  prep_k<<<99648, 256, 0, stream>>>(emb, mask, Wkt, Wout, mge, Wk, Wv, Wqs, Wqc,
                                    embB, mbit, WktB, WoutB, mgeB, WkT, WvT, WqsT, WqcT);
  wfqc_k<<<24, 256, 0, stream>>>(WktB, WoutB, WFT, mgeB, WqcT, Qc);
  gemmq_k<<<768, 512, 0, stream>>>(embB, WqsT, Qb, Qc, Wqs + 512 * 512, cap, prev,
                                   WkT, WvT, Kb, Vt);
  attn5_k<<<2048, 512, 0, stream>>>(Qb, Kb, Vt, mbit, mhaB);
  gemm11_k<<<256, 512, 0, stream>>>(mhaB, WFT, mh2);
  comp5_k<<<512, 512, 0, stream>>>(mh2, embB, mbit, out, sums);
  norm_k<<<8192, 256, 0, stream>>>(out, sums);
}

// Round 20
// 484.676 us; speedup vs baseline: 1.0252x; 1.0048x over previous
//
#include <hip/hip_runtime.h>
#include <hip/hip_bf16.h>

// Problem constants
constexpr int Bb = 256;   // batch
constexpr int Nn = 512;   // nodes
constexpr int Dd = 512;   // model dim
constexpr int Hh = 8;     // heads
constexpr int Tt = 128;   // steps
#define NEGF (-1.0e9f)

typedef __attribute__((ext_vector_type(4))) float f32x4;
typedef __attribute__((ext_vector_type(8))) short bf16x8;     // MFMA a/b frag (8 bf16)
typedef __attribute__((ext_vector_type(8))) unsigned short u16x8;

#define AS1 __attribute__((address_space(1)))
#define AS3 __attribute__((address_space(3)))

__device__ __forceinline__ unsigned short f2bf(float f) {
  union { float f; unsigned u; } v; v.f = f;
  unsigned r = v.u + 0x7fffu + ((v.u >> 16) & 1u);   // RNE
  return (unsigned short)(r >> 16);
}

__device__ __forceinline__ unsigned cvtpk(float lo, float hi) {
  unsigned r;
  asm("v_cvt_pk_bf16_f32 %0, %1, %2" : "=v"(r) : "v"(lo), "v"(hi));
  return r;
}

__device__ __forceinline__ void cast8(const float* __restrict__ src,
                                      unsigned short* __restrict__ dst, int i) {
  const float4* s = (const float4*)src + (size_t)i * 2;
  float4 a = s[0], b = s[1];
  u16x8 o;
  o[0] = f2bf(a.x); o[1] = f2bf(a.y); o[2] = f2bf(a.z); o[3] = f2bf(a.w);
  o[4] = f2bf(b.x); o[5] = f2bf(b.y); o[6] = f2bf(b.z); o[7] = f2bf(b.w);
  ((u16x8*)dst)[i] = o;
}

// ======== prep_k: fused prologue (casts + mask bitmask + weight transpose-casts) ========
__global__ void prep_k(const float* __restrict__ emb, const int* __restrict__ mask,
                       const float* __restrict__ Wkt, const float* __restrict__ Wout,
                       const float* __restrict__ mge,
                       const float* __restrict__ Wk, const float* __restrict__ Wv,
                       const float* __restrict__ Wqs, const float* __restrict__ Wqc,
                       unsigned short* __restrict__ embB, unsigned* __restrict__ bits,
                       unsigned short* __restrict__ WktB, unsigned short* __restrict__ WoutB,
                       unsigned short* __restrict__ mgeB,
                       unsigned short* __restrict__ WkT, unsigned short* __restrict__ WvT,
                       unsigned short* __restrict__ WqsT, unsigned short* __restrict__ WqcT) {
  __shared__ float t[32][33];
  int bid = blockIdx.x, tid = threadIdx.x;
  if (bid < 32768) {
    cast8(emb, embB, bid * 256 + tid);
  } else if (bid < 98304) {
    size_t gid = (size_t)(bid - 32768) * 256 + tid;
    int mv = mask[gid];
    unsigned long long bal = __ballot(mv == 1);
    if ((tid & 63) == 0) {
      unsigned tt = (unsigned)(gid >> 17);
      unsigned b = (unsigned)((gid >> 9) & 255);
      unsigned n = (unsigned)(gid & 511);
      unsigned* dst = bits + (((size_t)b * 128 + tt) * 16 + (n >> 5));
      dst[0] = (unsigned)bal;
      dst[1] = (unsigned)(bal >> 32);
    }
  } else if (bid < 98432) {
    cast8(Wkt, WktB, (bid - 98304) * 256 + tid);
  } else if (bid < 98560) {
    cast8(Wout, WoutB, (bid - 98432) * 256 + tid);
  } else if (bid < 98624) {
    cast8(mge, mgeB, (bid - 98560) * 256 + tid);
  } else {
    int vb = bid - 98624;
    int mid = vb >> 8;
    int tile = vb & 255;
    const float* S = (mid == 0) ? Wk : (mid == 1) ? Wv : (mid == 2) ? Wqs : Wqc;
    unsigned short* Dst = (mid == 0) ? WkT : (mid == 1) ? WvT : (mid == 2) ? WqsT : WqcT;
    int r0 = (tile >> 4) * 32, c0 = (tile & 15) * 32;
    int tx = tid & 31, ty = tid >> 5;
#pragma unroll
    for (int yy = 0; yy < 4; ++yy) {
      int r = ty + yy * 8;
      t[r][tx] = S[(size_t)(r0 + r) * 512 + c0 + tx];
    }
    __syncthreads();
#pragma unroll
    for (int yy = 0; yy < 4; ++yy) {
      int c = ty + yy * 8;
      Dst[(size_t)(c0 + c) * 512 + r0 + tx] = f2bf(t[tx][c]);   // Dst[n][k] = W[k][n]
    }
  }
}

// ---------------- shared staging: 128x64 bf16 tile via global_load_lds (16B) ----------------
__device__ __forceinline__ void stage_tile(const unsigned short* __restrict__ G, int row0, int k0,
                                           unsigned short* lds_base, int wave, int lane) {
#pragma unroll
  for (int c = 0; c < 4; ++c) {
    int chunk = wave * 4 + c;                       // 16 chunks of 1KB (8 rows each)
    const unsigned short* g = G + (size_t)(row0 + chunk * 8 + (lane >> 3)) * 512 + k0 + (lane & 7) * 8;
    __builtin_amdgcn_global_load_lds((AS1 void*)g, (AS3 void*)(lds_base + chunk * 512), 16, 0, 0);
  }
}

// ======== wfqc_k: merged tiny GEMMs — blocks 0-15: WFT=WktB@WoutB^T (bf16);
//          blocks 16-23: Qc=mgeB@WqcT^T (f32) ========
__global__ __launch_bounds__(256, 2)
void wfqc_k(const unsigned short* __restrict__ A0, const unsigned short* __restrict__ BT0,
            unsigned short* __restrict__ C0,
            const unsigned short* __restrict__ A1, const unsigned short* __restrict__ BT1,
            float* __restrict__ C1) {
  __shared__ __align__(16) char lds[32768];
  unsigned short* ldsA = (unsigned short*)lds;
  unsigned short* ldsB = ldsA + 8192;
  int bid = blockIdx.x;
  bool qc = (bid >= 16);
  int lb = qc ? bid - 16 : bid;
  const unsigned short* A = qc ? A1 : A0;
  const unsigned short* BT = qc ? BT1 : BT0;
  int mt = lb >> 2, nt = lb & 3;
  int m0 = mt * 128, n0 = nt * 128;
  int tid = threadIdx.x, lane = tid & 63, w = tid >> 6;
  int wm = w >> 1, wn = w & 1;
  int l15 = lane & 15, l4 = lane >> 4;

  f32x4 acc[4][4] = {};
  for (int k0 = 0; k0 < 512; k0 += 64) {
    stage_tile(A, m0, k0, ldsA, w, lane);
    stage_tile(BT, n0, k0, ldsB, w, lane);
    __syncthreads();
#pragma unroll
    for (int ks = 0; ks < 2; ++ks) {
      bf16x8 fa[4], fb[4];
#pragma unroll
      for (int ii = 0; ii < 4; ++ii)
        fa[ii] = *(const bf16x8*)(ldsA + (wm * 64 + ii * 16 + l15) * 64 + ks * 32 + l4 * 8);
#pragma unroll
      for (int jj = 0; jj < 4; ++jj)
        fb[jj] = *(const bf16x8*)(ldsB + (wn * 64 + jj * 16 + l15) * 64 + ks * 32 + l4 * 8);
#pragma unroll
      for (int ii = 0; ii < 4; ++ii)
#pragma unroll
        for (int jj = 0; jj < 4; ++jj)
          acc[ii][jj] = __builtin_amdgcn_mfma_f32_16x16x32_bf16(fa[ii], fb[jj], acc[ii][jj], 0, 0, 0);
    }
    __syncthreads();
  }
#pragma unroll
  for (int ii = 0; ii < 4; ++ii)
#pragma unroll
    for (int jj = 0; jj < 4; ++jj)
#pragma unroll
      for (int r = 0; r < 4; ++r) {
        int row = m0 + wm * 64 + ii * 16 + l4 * 4 + r;
        int col = n0 + wn * 64 + jj * 16 + l15;
        if (qc) C1[(size_t)row * 512 + col] = acc[ii][jj][r];
        else C0[(size_t)row * 512 + col] = f2bf(acc[ii][jj][r]);
      }
}

// ---------------- shared 8-phase macros (proven in gemm8f/gemm10/gemm11) ----------------
#define LDA_Q(QM)                                                   \
  _Pragma("unroll")                                                 \
  for (int ii = 0; ii < 4; ++ii) {                                  \
    int rr_ = (QM) * 64 + ii * 16 + l15;                            \
    const char* ap_ = ldsAh + rr_ * 128;                            \
    int sw_ = (rr_ & 7) << 4;                                       \
    fa[ii][0] = *(const bf16x8*)(ap_ + ((l4 * 16) ^ sw_));          \
    fa[ii][1] = *(const bf16x8*)(ap_ + ((64 + l4 * 16) ^ sw_));     \
  }

#define LDB_Q(QN)                                                   \
  _Pragma("unroll")                                                 \
  for (int jj = 0; jj < 2; ++jj) {                                  \
    int rr_ = (wn & 1) * 64 + (QN) * 32 + jj * 16 + l15;            \
    const char* bp_ = ldsBh + rr_ * 128;                            \
    int sw_ = (rr_ & 7) << 4;                                       \
    fb[jj][0] = *(const bf16x8*)(bp_ + ((l4 * 16) ^ sw_));          \
    fb[jj][1] = *(const bf16x8*)(bp_ + ((64 + l4 * 16) ^ sw_));     \
  }

#define MM16(QM, QN)                                                              \
  do {                                                                            \
    __builtin_amdgcn_s_setprio(1);                                                \
    _Pragma("unroll")                                                             \
    for (int ii = 0; ii < 4; ++ii)                                                \
      _Pragma("unroll")                                                           \
      for (int jj = 0; jj < 2; ++jj) {                                            \
        acc[(QM) * 4 + ii][(QN) * 2 + jj] = __builtin_amdgcn_mfma_f32_16x16x32_bf16( \
            fa[ii][0], fb[jj][0], acc[(QM) * 4 + ii][(QN) * 2 + jj], 0, 0, 0);    \
        acc[(QM) * 4 + ii][(QN) * 2 + jj] = __builtin_amdgcn_mfma_f32_16x16x32_bf16( \
            fa[ii][1], fb[jj][1], acc[(QM) * 4 + ii][(QN) * 2 + jj], 0, 0, 0);    \
      }                                                                           \
    __builtin_amdgcn_s_setprio(0);                                                \
  } while (0)

// gemm10 staging (persistent double GEMM part)
#define STAGE10A(SLOT, H, ROWB, KT)                                               \
  do {                                                                             \
    int rb_ = (ROWB) + (H) * 128;                                                  \
    char* Lb_ = lds + (SLOT) * 32768 + (H) * 16384;                                \
    _Pragma("unroll")                                                              \
    for (int sh_ = 0; sh_ < 2; ++sh_) {                                            \
      int off_ = sh_ * 8192 + tid * 16;                                            \
      int r_ = off_ >> 7;                                                          \
      int c_ = (off_ & 127) ^ ((r_ & 7) << 4);                                     \
      const char* g_ = (const char*)(A + (size_t)(rb_ + r_) * 512 + (KT) * 64) + c_; \
      __builtin_amdgcn_global_load_lds((AS1 void*)g_, (AS3 void*)(Lb_ + off_), 16, 0, 0); \
    }                                                                              \
  } while (0)

#define STAGE10B(SLOT, H, KT)                                                      \
  do {                                                                             \
    int rb_ = n0 + (H) * 128;                                                      \
    char* Lb_ = lds + 98304 + (SLOT) * 32768 + (H) * 16384;                        \
    _Pragma("unroll")                                                              \
    for (int sh_ = 0; sh_ < 2; ++sh_) {                                            \
      int off_ = sh_ * 8192 + tid * 16;                                            \
      int r_ = off_ >> 7;                                                          \
      int c_ = (off_ & 127) ^ ((r_ & 7) << 4);                                     \
      const char* g_ = (const char*)(BT + (size_t)(rb_ + r_) * 512 + (KT) * 64) + c_; \
      __builtin_amdgcn_global_load_lds((AS1 void*)g_, (AS3 void*)(Lb_ + off_), 16, 0, 0); \
    }                                                                              \
  } while (0)

// gemm11 staging (single-tile q/mh2 part; A via per-thread bases, supports gather)
#define STAGE11A(SLOT, H, KT)                                                      \
  do {                                                                             \
    char* Lb_ = lds + (SLOT) * 65536 + (H) * 16384;                                \
    __builtin_amdgcn_global_load_lds((AS1 void*)(abase[(H) * 2 + 0] + (KT) * 128), \
        (AS3 void*)(Lb_ + tid * 16), 16, 0, 0);                                    \
    __builtin_amdgcn_global_load_lds((AS1 void*)(abase[(H) * 2 + 1] + (KT) * 128), \
        (AS3 void*)(Lb_ + 8192 + tid * 16), 16, 0, 0);                             \
  } while (0)

#define STAGE11B(SLOT, H, KT)                                                      \
  do {                                                                             \
    int rb_ = n0 + (H) * 128;                                                      \
    char* Lb_ = lds + (SLOT) * 65536 + 32768 + (H) * 16384;                        \
    _Pragma("unroll")                                                              \
    for (int sh_ = 0; sh_ < 2; ++sh_) {                                            \
      int off_ = sh_ * 8192 + tid * 16;                                            \
      int r_ = off_ >> 7;                                                          \
      int c_ = (off_ & 127) ^ ((r_ & 7) << 4);                                     \
      const char* g_ = (const char*)(BT + (size_t)(rb_ + r_) * 512 + (KT) * 64) + c_; \
      __builtin_amdgcn_global_load_lds((AS1 void*)g_, (AS3 void*)(Lb_ + off_), 16, 0, 0); \
    }                                                                              \
  } while (0)

// ======== gemmq_k: FUSED dispatch. blocks [0,256): gemm11<3> (Qb, gathered A).
//          blocks [256,512): gemm10 persistent 8-tile double GEMM (Kb + Vt). ========
__global__ __launch_bounds__(512, 1)
void gemmq_k(const unsigned short* __restrict__ embB,
             const unsigned short* __restrict__ WqsT,
             unsigned short* __restrict__ Qb,
             const float* __restrict__ Qc, const float* __restrict__ WqsL,
             const float* __restrict__ capp, const int* __restrict__ prev,
             const unsigned short* __restrict__ B0, const unsigned short* __restrict__ B1,
             unsigned short* __restrict__ C0, unsigned short* __restrict__ C2) {
  __shared__ __align__(16) char lds[163840];
  int tid = threadIdx.x, lane = tid & 63, w = tid >> 6;
  int l15 = lane & 15, l4 = lane >> 4;

  if (blockIdx.x < 256) {
    // ---------------- gemm11<3>: Qb projection with gathered A rows ----------------
    const unsigned short* A = embB;
    const unsigned short* BT = WqsT;
    int xcd = blockIdx.x & 7, loc = blockIdx.x >> 3;   // loc < 32
    int mt = xcd * 16 + (loc >> 1), nh = loc & 1;
    int m0 = mt * 256, n0 = nh * 256;
    int wm = w >> 2, wn = w & 3;

    const char* abase[4];
#pragma unroll
    for (int hs = 0; hs < 4; ++hs) {
      int H = hs >> 1, sh = hs & 1;
      int off = sh * 8192 + tid * 16;
      int r = off >> 7;
      int c = (off & 127) ^ ((r & 7) << 4);
      int row = m0 + H * 128 + r;
      int t = row >> 8, bb = row & 255;
      int pa = prev[t * Bb + bb];
      abase[hs] = (const char*)(A + (size_t)(bb * 512 + pa) * 512) + c;
    }

    f32x4 acc[8][4] = {};
    bf16x8 fa[4][2], fb[2][2];

    STAGE11A(0, 0, 0); STAGE11A(0, 1, 0);
    STAGE11B(0, 0, 0); STAGE11B(0, 1, 0);

    for (int kt = 0; kt < 8; ++kt) {
      int s = kt & 1, sn = s ^ 1;
      char* ldsAh = lds + s * 65536 + wm * 16384;
      char* ldsBh = lds + s * 65536 + 32768 + (wn >> 1) * 16384;
      if (kt < 7) {
        STAGE11A(sn, 0, kt + 1);
        asm volatile("s_waitcnt vmcnt(2)" ::: "memory");
      } else {
        asm volatile("s_waitcnt vmcnt(0)" ::: "memory");
      }
      __builtin_amdgcn_s_barrier();
      LDA_Q(0); LDB_Q(0);
      MM16(0, 0);
      __builtin_amdgcn_s_barrier();
      LDB_Q(1);
      if (kt < 7) STAGE11A(sn, 1, kt + 1);
      __builtin_amdgcn_s_barrier();
      MM16(0, 1);
      __builtin_amdgcn_s_barrier();
      LDA_Q(1);
      if (kt < 7) STAGE11B(sn, 0, kt + 1);
      __builtin_amdgcn_s_barrier();
      MM16(1, 1);
      __builtin_amdgcn_s_barrier();
      LDB_Q(0);
      if (kt < 7) STAGE11B(sn, 1, kt + 1);
      __builtin_amdgcn_s_barrier();
      MM16(1, 0);
      __builtin_amdgcn_s_barrier();
    }

#pragma unroll
    for (int mi = 0; mi < 8; ++mi)
#pragma unroll
      for (int nj = 0; nj < 4; ++nj)
#pragma unroll
        for (int r = 0; r < 4; ++r) {
          int row = m0 + wm * 128 + mi * 16 + l4 * 4 + r;
          int col = n0 + wn * 64 + nj * 16 + l15;
          int t = row >> 8, bbx = row & 255;
          float val = acc[mi][nj][r] + Qc[(size_t)bbx * 512 + col] + (1.0f - capp[row]) * WqsL[col];
          Qb[(size_t)(bbx * 128 + t) * 512 + col] = f2bf(val * 0.125f);
        }
  } else {
    // ---------------- gemm10: persistent 8-tile fused double GEMM (K / V^T) ----------------
    const unsigned short* A = embB;
    int bid = blockIdx.x - 256;
    int xcd = bid & 7, loc = bid >> 3;   // loc < 32
    int ml8 = loc >> 2, cmb = loc & 3;
    int grp = cmb >> 1, nh = cmb & 1;
    const unsigned short* BT = grp ? B1 : B0;
    int mtb = xcd * 64 + ml8 * 8;        // first of 8 m-tiles (256 rows each)
    int n0 = nh * 256;
    int wm = w >> 2, wn = w & 3;

    f32x4 acc[8][4] = {};
    bf16x8 fa[4][2], fb[2][2];

    {
      int m00 = mtb * 256;
      STAGE10A(0, 0, m00, 0); STAGE10A(0, 1, m00, 0);
      STAGE10A(1, 0, m00, 1); STAGE10A(1, 1, m00, 1);
      STAGE10B(0, 0, 0);      STAGE10B(0, 1, 0);
    }

    for (int g = 0; g < 64; ++g) {
      int As = g % 3, Astg = (g + 2) % 3;
      int Bs = g & 1, Bstg = Bs ^ 1;
      char* ldsAh = lds + As * 32768 + wm * 16384;
      char* ldsBh = lds + 98304 + Bs * 32768 + (wn >> 1) * 16384;
      int g2 = g + 2;
      int m0A = (mtb + (g2 >> 3)) * 256, ktA = g2 & 7;
      int ktB = (g + 1) & 7;
      if (g < 62) {
        STAGE10A(Astg, 0, m0A, ktA);
        asm volatile("s_waitcnt vmcnt(2)" ::: "memory");
      } else {
        asm volatile("s_waitcnt vmcnt(0)" ::: "memory");
      }
      __builtin_amdgcn_s_barrier();
      LDA_Q(0); LDB_Q(0);
      MM16(0, 0);
      __builtin_amdgcn_s_barrier();
      LDB_Q(1);
      if (g < 62) STAGE10A(Astg, 1, m0A, ktA);
      __builtin_amdgcn_s_barrier();
      MM16(0, 1);
      __builtin_amdgcn_s_barrier();
      LDA_Q(1);
      if (g < 63) STAGE10B(Bstg, 0, ktB);
      __builtin_amdgcn_s_barrier();
      MM16(1, 1);
      __builtin_amdgcn_s_barrier();
      LDB_Q(0);
      if (g < 63) STAGE10B(Bstg, 1, ktB);
      __builtin_amdgcn_s_barrier();
      MM16(1, 0);
      __builtin_amdgcn_s_barrier();

      if ((g & 7) == 7) {
        int m0cur = (mtb + (g >> 3)) * 256;
        if (grp == 0) {
#pragma unroll
          for (int mi = 0; mi < 8; ++mi)
#pragma unroll
            for (int nj = 0; nj < 4; ++nj)
#pragma unroll
              for (int r = 0; r < 4; ++r) {
                int row = m0cur + wm * 128 + mi * 16 + l4 * 4 + r;
                int col = n0 + wn * 64 + nj * 16 + l15;
                C0[(size_t)row * 512 + col] = f2bf(acc[mi][nj][r]);
              }
        } else {
          int bb = m0cur >> 9, nn0 = m0cur & 511;
          char* wb = lds + As * 32768 + w * 4096;   // dead A slot until ph0 of g+1
          int rdrow = lane >> 3, nseg = lane & 7;
#pragma unroll
          for (int p = 0; p < 8; ++p) {
            int nj = p >> 1;
            if ((l15 >> 3) == (p & 1)) {
              int rowL = l15 & 7;
#pragma unroll
              for (int mi = 0; mi < 8; ++mi) {
                ushort4 w4;
                w4.x = f2bf(acc[mi][nj][0]);
                w4.y = f2bf(acc[mi][nj][1]);
                w4.z = f2bf(acc[mi][nj][2]);
                w4.w = f2bf(acc[mi][nj][3]);
                *(ushort4*)(wb + rowL * 272 + (mi * 16 + l4 * 4) * 2) = w4;
              }
            }
            asm volatile("s_waitcnt lgkmcnt(0)" ::: "memory");
            u16x8 v0 = *(const u16x8*)(wb + rdrow * 272 + nseg * 16);
            u16x8 v1 = *(const u16x8*)(wb + rdrow * 272 + 128 + nseg * 16);
            int dglob = n0 + wn * 64 + p * 8 + rdrow;
            unsigned short* dp = C2 + (size_t)(bb * 512 + dglob) * 512 + nn0 + wm * 128;
            *(u16x8*)(dp + nseg * 8) = v0;
            *(u16x8*)(dp + 64 + nseg * 8) = v1;
            asm volatile("s_waitcnt lgkmcnt(0)" ::: "memory");
          }
        }
#pragma unroll
        for (int mi = 0; mi < 8; ++mi)
#pragma unroll
          for (int nj = 0; nj < 4; ++nj)
            acc[mi][nj] = (f32x4){0.f, 0.f, 0.f, 0.f};
        __syncthreads();
      }
    }
  }
}

// ======== gemm11<1>: 256x256 8-phase single-tile GEMM (mh2 = mhaB @ WFT^T) ========
__global__ __launch_bounds__(512, 1)
void gemm11_k(const unsigned short* __restrict__ A, const unsigned short* __restrict__ BT,
              unsigned short* __restrict__ C) {
  __shared__ __align__(16) char lds[131072];
  int xcd = blockIdx.x & 7, loc = blockIdx.x >> 3;   // loc < 32
  int mt = xcd * 16 + (loc >> 1), nh = loc & 1;
  int m0 = mt * 256, n0 = nh * 256;
  int tid = threadIdx.x, lane = tid & 63, w = tid >> 6;
  int wm = w >> 2, wn = w & 3;
  int l15 = lane & 15, l4 = lane >> 4;

  const char* abase[4];
#pragma unroll
  for (int hs = 0; hs < 4; ++hs) {
    int H = hs >> 1, sh = hs & 1;
    int off = sh * 8192 + tid * 16;
    int r = off >> 7;
    int c = (off & 127) ^ ((r & 7) << 4);
    int row = m0 + H * 128 + r;
    abase[hs] = (const char*)(A + (size_t)row * 512) + c;
  }

  f32x4 acc[8][4] = {};
  bf16x8 fa[4][2], fb[2][2];

  STAGE11A(0, 0, 0); STAGE11A(0, 1, 0);
  STAGE11B(0, 0, 0); STAGE11B(0, 1, 0);

  for (int kt = 0; kt < 8; ++kt) {
    int s = kt & 1, sn = s ^ 1;
    char* ldsAh = lds + s * 65536 + wm * 16384;
    char* ldsBh = lds + s * 65536 + 32768 + (wn >> 1) * 16384;
    if (kt < 7) {
      STAGE11A(sn, 0, kt + 1);
      asm volatile("s_waitcnt vmcnt(2)" ::: "memory");
    } else {
      asm volatile("s_waitcnt vmcnt(0)" ::: "memory");
    }
    __builtin_amdgcn_s_barrier();
    LDA_Q(0); LDB_Q(0);
    MM16(0, 0);
    __builtin_amdgcn_s_barrier();
    LDB_Q(1);
    if (kt < 7) STAGE11A(sn, 1, kt + 1);
    __builtin_amdgcn_s_barrier();
    MM16(0, 1);
    __builtin_amdgcn_s_barrier();
    LDA_Q(1);
    if (kt < 7) STAGE11B(sn, 0, kt + 1);
    __builtin_amdgcn_s_barrier();
    MM16(1, 1);
    __builtin_amdgcn_s_barrier();
    LDB_Q(0);
    if (kt < 7) STAGE11B(sn, 1, kt + 1);
    __builtin_amdgcn_s_barrier();
    MM16(1, 0);
    __builtin_amdgcn_s_barrier();
  }

#pragma unroll
  for (int mi = 0; mi < 8; ++mi)
#pragma unroll
    for (int nj = 0; nj < 4; ++nj)
#pragma unroll
      for (int r = 0; r < 4; ++r) {
        int row = m0 + wm * 128 + mi * 16 + l4 * 4 + r;
        int col = n0 + wn * 64 + nj * 16 + l15;
        C[(size_t)row * 512 + col] = f2bf(acc[mi][nj][r]);
      }
}

// ================= attn5: LDS-staged chunked flash pipeline =================
#define STAGEK5(CH, SLOT)                                                          \
  do {                                                                             \
    _Pragma("unroll")                                                              \
    for (int sh_ = 0; sh_ < 2; ++sh_) {                                            \
      int off_ = sh_ * 8192 + tid * 16;                                            \
      int r_ = off_ >> 7;                                                          \
      int c_ = (off_ & 127) ^ ((r_ & 7) << 4);                                     \
      const char* g_ = (const char*)(Kb + (size_t)(b * 512 + (CH) * 128 + r_) * 512 + h * 64) + c_; \
      __builtin_amdgcn_global_load_lds((AS1 void*)g_, (AS3 void*)(lds + (SLOT) * 16384 + off_), 16, 0, 0); \
    }                                                                              \
  } while (0)

#define STAGEV5(CH, SLOT)                                                          \
  do {                                                                             \
    _Pragma("unroll")                                                              \
    for (int sh_ = 0; sh_ < 2; ++sh_) {                                            \
      int off_ = sh_ * 8192 + tid * 16;                                            \
      int r_ = off_ >> 8;                                                          \
      int c_ = (off_ & 255) ^ ((r_ & 7) << 4);                                     \
      const char* g_ = (const char*)(Vt + (size_t)(b * 512 + h * 64 + r_) * 512 + (CH) * 128) + c_; \
      __builtin_amdgcn_global_load_lds((AS1 void*)g_, (AS3 void*)(lds + 32768 + (SLOT) * 16384 + off_), 16, 0, 0); \
    }                                                                              \
  } while (0)

#define CHUNK5(CH)                                                                 \
  do {                                                                             \
    const char* Ks_ = lds + ((CH) & 1) * 16384;                                    \
    const char* Vs_ = lds + 32768 + ((CH) & 1) * 16384;                            \
    f32x4 sck[8];                                                                  \
    _Pragma("unroll")                                                              \
    for (int jj = 0; jj < 8; ++jj) sck[jj] = (f32x4){0.f, 0.f, 0.f, 0.f};          \
    _Pragma("unroll")                                                              \
    for (int jj = 0; jj < 8; ++jj) {                                               \
      int rr_ = jj * 16 + l15;                                                     \
      int sw_ = (rr_ & 7) << 4;                                                    \
      bf16x8 k0_ = *(const bf16x8*)(Ks_ + rr_ * 128 + ((l4 * 16) ^ sw_));          \
      bf16x8 k1_ = *(const bf16x8*)(Ks_ + rr_ * 128 + ((64 + l4 * 16) ^ sw_));     \
      sck[jj] = __builtin_amdgcn_mfma_f32_16x16x32_bf16(k0_, fq[0], sck[jj], 0, 0, 0); \
      sck[jj] = __builtin_amdgcn_mfma_f32_16x16x32_bf16(k1_, fq[1], sck[jj], 0, 0, 0); \
    }                                                                              \
    unsigned mwarr_[4] = {mqs[CH].x, mqs[CH].y, mqs[CH].z, mqs[CH].w};             \
    float cmx_ = -3.0e38f;                                                         \
    _Pragma("unroll")                                                              \
    for (int jj = 0; jj < 8; ++jj) {                                               \
      unsigned nib_ = mwarr_[jj >> 1] >> (((jj & 1) << 4) + (l4 << 2));            \
      _Pragma("unroll")                                                            \
      for (int r = 0; r < 4; ++r)                                                  \
        sck[jj][r] = ((nib_ >> r) & 1) ? NEGF : sck[jj][r];                        \
      float m01_ = fmaxf(sck[jj][0], sck[jj][1]);                                  \
      float m23_ = fmaxf(sck[jj][2], sck[jj][3]);                                  \
      cmx_ = fmaxf(cmx_, fmaxf(m01_, m23_));                                       \
    }                                                                              \
    cmx_ = fmaxf(cmx_, __shfl_xor(cmx_, 16));                                      \
    cmx_ = fmaxf(cmx_, __shfl_xor(cmx_, 32));                                      \
    float mn_ = fmaxf(mx, cmx_);                                                   \
    float al_ = __expf(mx - mn_);                                                  \
    sum *= al_;                                                                    \
    _Pragma("unroll")                                                              \
    for (int dj = 0; dj < 4; ++dj)                                                 \
      _Pragma("unroll")                                                            \
      for (int r = 0; r < 4; ++r) o[dj][r] *= al_;                                 \
    mx = mn_;                                                                      \
    _Pragma("unroll")                                                              \
    for (int jj = 0; jj < 8; ++jj) {                                               \
      _Pragma("unroll")                                                            \
      for (int r = 0; r < 4; ++r) sck[jj][r] = __expf(sck[jj][r] - mx);            \
      sum += (sck[jj][0] + sck[jj][1]) + (sck[jj][2] + sck[jj][3]);                \
    }                                                                              \
    _Pragma("unroll")                                                              \
    for (int g = 0; g < 4; ++g) {                                                  \
      unsigned a0_ = cvtpk(sck[2 * g][0], sck[2 * g][1]);                          \
      unsigned a1_ = cvtpk(sck[2 * g][2], sck[2 * g][3]);                          \
      unsigned b0_ = cvtpk(sck[2 * g + 1][0], sck[2 * g + 1][1]);                  \
      unsigned b1_ = cvtpk(sck[2 * g + 1][2], sck[2 * g + 1][3]);                  \
      unsigned wA0_ = __shfl(a0_, src0, 64), wB0_ = __shfl(b0_, src0, 64);         \
      unsigned wA1_ = __shfl(a1_, src0, 64), wB1_ = __shfl(b1_, src0, 64);         \
      unsigned wA2_ = __shfl(a0_, src2, 64), wB2_ = __shfl(b0_, src2, 64);         \
      unsigned wA3_ = __shfl(a1_, src2, 64), wB3_ = __shfl(b1_, src2, 64);         \
      union { unsigned u[4]; bf16x8 v; } pu_;                                      \
      pu_.u[0] = loh ? wA0_ : wB0_;                                                \
      pu_.u[1] = loh ? wA1_ : wB1_;                                                \
      pu_.u[2] = loh ? wA2_ : wB2_;                                                \
      pu_.u[3] = loh ? wA3_ : wB3_;                                                \
      _Pragma("unroll")                                                            \
      for (int dj = 0; dj < 4; ++dj) {                                             \
        int rr_ = dj * 16 + l15;                                                   \
        int sw_ = (rr_ & 7) << 4;                                                  \
        bf16x8 fv_ = *(const bf16x8*)(Vs_ + rr_ * 256 + ((g * 64 + l4 * 16) ^ sw_)); \
        o[dj] = __builtin_amdgcn_mfma_f32_16x16x32_bf16(fv_, pu_.v, o[dj], 0, 0, 0); \
      }                                                                            \
    }                                                                              \
  } while (0)

__global__ __launch_bounds__(512, 4)
void attn5_k(const unsigned short* __restrict__ Qb, const unsigned short* __restrict__ Kb,
             const unsigned short* __restrict__ Vt, const unsigned* __restrict__ mbits,
             unsigned short* __restrict__ mhaB) {
  __shared__ __align__(16) char lds[65536];
  int bid = blockIdx.x;
  int h = bid & 7, b = bid >> 3;
  int tid = threadIdx.x, lane = tid & 63, w = tid >> 6;
  int l15 = lane & 15, l4 = lane >> 4;
  int t = w * 16 + l15;

  bf16x8 fq[2];
#pragma unroll
  for (int ks = 0; ks < 2; ++ks)
    fq[ks] = *(const bf16x8*)(Qb + (size_t)(b * 128 + t) * 512 + h * 64 + ks * 32 + l4 * 8);
  uint4 mqs[4];
  {
    const uint4* mp = (const uint4*)(mbits + (((size_t)b * 128 + t) << 4));
    mqs[0] = mp[0]; mqs[1] = mp[1]; mqs[2] = mp[2]; mqs[3] = mp[3];
  }

  float mx = -3.0e38f, sum = 0.f;
  f32x4 o[4] = {};
  int src0 = l15 + ((l4 & 1) ? 32 : 0);
  int src2 = l15 + ((l4 & 1) ? 48 : 16);
  bool loh = (l4 < 2);

  STAGEK5(0, 0); STAGEV5(0, 0);
  STAGEK5(1, 1); STAGEV5(1, 1);
  asm volatile("s_waitcnt vmcnt(4)" ::: "memory");
  __builtin_amdgcn_s_barrier();
  CHUNK5(0);
  __builtin_amdgcn_s_barrier();
  STAGEK5(2, 0); STAGEV5(2, 0);
  asm volatile("s_waitcnt vmcnt(4)" ::: "memory");
  __builtin_amdgcn_s_barrier();
  CHUNK5(1);
  __builtin_amdgcn_s_barrier();
  STAGEK5(3, 1); STAGEV5(3, 1);
  asm volatile("s_waitcnt vmcnt(4)" ::: "memory");
  __builtin_amdgcn_s_barrier();
  CHUNK5(2);
  __builtin_amdgcn_s_barrier();
  asm volatile("s_waitcnt vmcnt(0)" ::: "memory");
  __builtin_amdgcn_s_barrier();
  CHUNK5(3);

  sum += __shfl_xor(sum, 16);
  sum += __shfl_xor(sum, 32);
  float inv = 1.0f / sum;
#pragma unroll
  for (int dj = 0; dj < 4; ++dj) {
    ushort4 w4;
    w4.x = f2bf(o[dj][0] * inv);
    w4.y = f2bf(o[dj][1] * inv);
    w4.z = f2bf(o[dj][2] * inv);
    w4.w = f2bf(o[dj][3] * inv);
    *(ushort4*)(mhaB + (size_t)(b * 128 + t) * 512 + h * 64 + dj * 16 + l4 * 4) = w4;
  }
}

// ========= comp5: n-split (b, nh) pointer logits, 32-row chunks, 2 blocks/CU =========
#define STAGEC5(CH, SLOT)                                                          \
  do {                                                                             \
    _Pragma("unroll")                                                              \
    for (int ps_ = 0; ps_ < 4; ++ps_) {                                            \
      int off_ = ps_ * 8192 + tid * 16;                                            \
      int r_ = off_ >> 10;                                                         \
      int c_ = (off_ & 1023) ^ ((r_ & 7) << 4);                                    \
      const char* g_ = (const char*)(embB + (size_t)(b * 512 + nh * 256 + (CH) * 32 + r_) * 512) + c_; \
      __builtin_amdgcn_global_load_lds((AS1 void*)g_, (AS3 void*)(lds + (SLOT) * 32768 + off_), 16, 0, 0); \
    }                                                                              \
  } while (0)

#define CCHUNK5(CH)                                                                \
  do {                                                                             \
    const char* Es_ = lds + ((CH) & 1) * 32768;                                    \
    _Pragma("unroll")                                                              \
    for (int jjl_ = 0; jjl_ < 2; ++jjl_) {                                         \
      f32x4 sck = (f32x4){0.f, 0.f, 0.f, 0.f};                                     \
      int rr_ = jjl_ * 16 + l15;                                                   \
      const char* ep_ = Es_ + rr_ * 1024;                                          \
      int sw_ = (rr_ & 7) << 4;                                                    \
      _Pragma("unroll")                                                            \
      for (int ks_ = 0; ks_ < 16; ++ks_) {                                         \
        bf16x8 fa_ = *(const bf16x8*)(ep_ + ((ks_ * 64 + l4 * 16) ^ sw_));         \
        sck = __builtin_amdgcn_mfma_f32_16x16x32_bf16(fa_, fb[ks_], sck, 0, 0, 0); \
      }                                                                            \
      unsigned nib_ = mwh[CH] >> ((jjl_ << 4) + (l4 << 2));                        \
      float4 o4_;                                                                  \
      float* po_ = (float*)&o4_;                                                   \
      _Pragma("unroll")                                                            \
      for (int r = 0; r < 4; ++r) {                                                \
        float y_ = sck[r] * 0.044194173824159216f;                                 \
        y_ = fminf(fmaxf(y_, -15.f), 15.f);                                        \
        float e2_ = __expf(2.f * y_);                                              \
        float th_ = (e2_ - 1.f) / (e2_ + 1.f);                                     \
        float p_ = __expf(th_ * 10.f - 10.f);                                      \
        p_ = ((nib_ >> r) & 1) ? 0.f : p_;                                         \
        po_[r] = p_;                                                               \
        sum += p_;                                                                 \
      }                                                                            \
      *(float4*)(out + (size_t)(b * 128 + t) * 512 + nh * 256 + (CH) * 32 + jjl_ * 16 + l4 * 4) = o4_; \
    }                                                                              \
  } while (0)

__global__ __launch_bounds__(512, 2)
void comp5_k(const unsigned short* __restrict__ mh2, const unsigned short* __restrict__ embB,
             const unsigned* __restrict__ mbits, float* __restrict__ out,
             float* __restrict__ sums) {
  __shared__ __align__(16) char lds[65536];
  int b = blockIdx.x >> 1, nh = blockIdx.x & 1;
  int tid = threadIdx.x, lane = tid & 63, w = tid >> 6;
  int l15 = lane & 15, l4 = lane >> 4;
  int t = w * 16 + l15;

  bf16x8 fb[16];
#pragma unroll
  for (int ks = 0; ks < 16; ++ks)
    fb[ks] = *(const bf16x8*)(mh2 + (size_t)(b * 128 + t) * 512 + ks * 32 + l4 * 8);
  unsigned mwh[8];
  {
    const uint4* mp = (const uint4*)(mbits + (((size_t)b * 128 + t) << 4)) + nh * 2;
    uint4 a0 = mp[0], a1 = mp[1];
    mwh[0] = a0.x; mwh[1] = a0.y; mwh[2] = a0.z; mwh[3] = a0.w;
    mwh[4] = a1.x; mwh[5] = a1.y; mwh[6] = a1.z; mwh[7] = a1.w;
  }

  float sum = 0.f;
  STAGEC5(0, 0);
  STAGEC5(1, 1);
  asm volatile("s_waitcnt vmcnt(4)" ::: "memory");
  __builtin_amdgcn_s_barrier();
  CCHUNK5(0);
  __builtin_amdgcn_s_barrier();
  STAGEC5(2, 0);
  asm volatile("s_waitcnt vmcnt(4)" ::: "memory");
  __builtin_amdgcn_s_barrier();
  CCHUNK5(1);
  __builtin_amdgcn_s_barrier();
  STAGEC5(3, 1);
  asm volatile("s_waitcnt vmcnt(4)" ::: "memory");
  __builtin_amdgcn_s_barrier();
  CCHUNK5(2);
  __builtin_amdgcn_s_barrier();
  STAGEC5(4, 0);
  asm volatile("s_waitcnt vmcnt(4)" ::: "memory");
  __builtin_amdgcn_s_barrier();
  CCHUNK5(3);
  __builtin_amdgcn_s_barrier();
  STAGEC5(5, 1);
  asm volatile("s_waitcnt vmcnt(4)" ::: "memory");
  __builtin_amdgcn_s_barrier();
  CCHUNK5(4);
  __builtin_amdgcn_s_barrier();
  STAGEC5(6, 0);
  asm volatile("s_waitcnt vmcnt(4)" ::: "memory");
  __builtin_amdgcn_s_barrier();
  CCHUNK5(5);
  __builtin_amdgcn_s_barrier();
  STAGEC5(7, 1);
  asm volatile("s_waitcnt vmcnt(4)" ::: "memory");
  __builtin_amdgcn_s_barrier();
  CCHUNK5(6);
  __builtin_amdgcn_s_barrier();
  asm volatile("s_waitcnt vmcnt(0)" ::: "memory");
  __builtin_amdgcn_s_barrier();
  CCHUNK5(7);

  sum += __shfl_xor(sum, 16);
  sum += __shfl_xor(sum, 32);
  if (l4 == 0) sums[nh * 32768 + b * 128 + t] = sum;
}

// ---------------- normalize: out[row][:] *= 1/(s0[row]+s1[row]) ----------------
__global__ void norm_k(float* __restrict__ out, const float* __restrict__ sums) {
  int row = blockIdx.x * 4 + (threadIdx.x >> 6);
  int lane = threadIdx.x & 63;
  float inv = 1.0f / (sums[row] + sums[32768 + row]);
  float4* p = (float4*)(out + (size_t)row * 512) + lane;
  float4 a = p[0], b = p[64];
  a.x *= inv; a.y *= inv; a.z *= inv; a.w *= inv;
  b.x *= inv; b.y *= inv; b.z *= inv; b.w *= inv;
  p[0] = a; p[64] = b;
}

extern "C" void kernel_launch(void* const* d_in, const int* in_sizes, int n_in,
                              void* d_out, int out_size, void* d_ws, size_t ws_size,
                              hipStream_t stream) {
  (void)in_sizes; (void)n_in; (void)out_size; (void)ws_size;
  const float* emb  = (const float*)d_in[0];
  const float* mge  = (const float*)d_in[1];
  const float* cap  = (const float*)d_in[2];
  const float* Wk   = (const float*)d_in[3];
  const float* Wkt  = (const float*)d_in[4];
  const float* Wv   = (const float*)d_in[5];
  const float* Wqc  = (const float*)d_in[6];
  const float* Wqs  = (const float*)d_in[7];
  const float* Wout = (const float*)d_in[8];
  const int* prev   = (const int*)d_in[9];
  const int* mask   = (const int*)d_in[10];
  float* out = (float*)d_out;

  char* p = (char*)d_ws;
  auto take = [&](size_t n) { char* q = p; p += (n + 255) & ~(size_t)255; return q; };
  unsigned short* embB = (unsigned short*)take((size_t)131072 * 512 * 2);
  unsigned short* Kb   = (unsigned short*)take((size_t)131072 * 512 * 2);
  unsigned short* Vt   = (unsigned short*)take((size_t)131072 * 512 * 2);
  unsigned short* Qb   = (unsigned short*)take((size_t)32768 * 512 * 2);
  unsigned short* mhaB = (unsigned short*)take((size_t)32768 * 512 * 2);
  unsigned short* mh2  = (unsigned short*)take((size_t)32768 * 512 * 2);
  float*          Qc   = (float*)take((size_t)256 * 512 * 4);
  unsigned*       mbit = (unsigned*)take((size_t)256 * 128 * 16 * 4);
  float*          sums = (float*)take((size_t)2 * 32768 * 4);
  unsigned short* WkT  = (unsigned short*)take(524288);
  unsigned short* WvT  = (unsigned short*)take(524288);
  unsigned short* WqsT = (unsigned short*)take(524288);
  unsigned short* WqcT = (unsigned short*)take(524288);
  unsigned short* WktB = (unsigned short*)take(524288);
  unsigned short* WoutB= (unsigned short*)take(524288);
  unsigned short* WFT  = (unsigned short*)take(524288);
  unsigned short* mgeB = (unsigned short*)take((size_t)256 * 512 * 2);

  prep_k<<<99648, 256, 0, stream>>>(emb, mask, Wkt, Wout, mge, Wk, Wv, Wqs, Wqc,
                                    embB, mbit, WktB, WoutB, mgeB, WkT, WvT, WqsT, WqcT);
  wfqc_k<<<24, 256, 0, stream>>>(WktB, WoutB, WFT, mgeB, WqcT, Qc);
  gemmq_k<<<512, 512, 0, stream>>>(embB, WqsT, Qb, Qc, Wqs + 512 * 512, cap, prev,
                                   WkT, WvT, Kb, Vt);
  attn5_k<<<2048, 512, 0, stream>>>(Qb, Kb, Vt, mbit, mhaB);
  gemm11_k<<<256, 512, 0, stream>>>(mhaB, WFT, mh2);
  comp5_k<<<512, 512, 0, stream>>>(mh2, embB, mbit, out, sums);
  norm_k<<<8192, 256, 0, stream>>>(out, sums);
}